// Round 1
// baseline (2716.147 us; speedup 1.0000x reference)
//
#include <hip/hip_runtime.h>
#include <math.h>

#define NN 10000
#define NE 160000
#define HIDN 128
#define HCW 512
#define NHEADS 4
#define CH 128
#define NLAYERS 4
#define LN_EPS 1e-5f

// ---------------- CSR build ----------------
__global__ void k_init(int* cnt, int* fill, float* stats) {
    int i = blockIdx.x * blockDim.x + threadIdx.x;
    if (i < NN) { cnt[i] = 0; fill[i] = 0; }
    if (i < 16) stats[i] = 0.f;
}

__global__ void k_count(const int* __restrict__ dst, int* __restrict__ cnt) {
    int e = blockIdx.x * blockDim.x + threadIdx.x;
    if (e < NE) atomicAdd(&cnt[dst[e]], 1);
}

__global__ __launch_bounds__(1024) void k_scan(const int* __restrict__ cnt, int* __restrict__ offs) {
    __shared__ int sh[1024];
    __shared__ int carry;
    if (threadIdx.x == 0) carry = 0;
    __syncthreads();
    for (int base = 0; base < NN; base += 1024) {
        int i = base + threadIdx.x;
        int v = (i < NN) ? cnt[i] : 0;
        sh[threadIdx.x] = v;
        __syncthreads();
        for (int off = 1; off < 1024; off <<= 1) {
            int t = (threadIdx.x >= off) ? sh[threadIdx.x - off] : 0;
            __syncthreads();
            sh[threadIdx.x] += t;
            __syncthreads();
        }
        int incl = sh[threadIdx.x];
        if (i < NN) offs[i] = carry + incl - v;   // exclusive
        __syncthreads();
        if (threadIdx.x == 1023) carry += sh[1023];
        __syncthreads();
    }
    if (threadIdx.x == 0) offs[NN] = carry;
}

__global__ void k_fill(const int* __restrict__ src, const int* __restrict__ dst,
                       const int* __restrict__ offs, int* __restrict__ fill,
                       int* __restrict__ col) {
    int e = blockIdx.x * blockDim.x + threadIdx.x;
    if (e < NE) {
        int d = dst[e];
        int p = offs[d] + atomicAdd(&fill[d], 1);
        col[p] = src[e];
    }
}

// ---------------- input projection: h = x @ W_in + b_in ----------------
__global__ __launch_bounds__(128) void k_inproj(const float* __restrict__ x,
                                                const float* __restrict__ W,
                                                const float* __restrict__ b,
                                                float* __restrict__ h) {
    int n = blockIdx.x;
    int j = threadIdx.x;
    float acc = b[j];
#pragma unroll
    for (int i = 0; i < 15; i++) acc += x[n * 15 + i] * W[i * 128 + j];
    h[n * 128 + j] = acc;
}

// ---------------- fused qkv+skip GEMM: [N,128] @ [128,512]x4 ----------------
__global__ __launch_bounds__(256) void k_qkvs(const float* __restrict__ h,
    const float* __restrict__ Wq, const float* __restrict__ Wk,
    const float* __restrict__ Wv, const float* __restrict__ Ws,
    const float* __restrict__ bq, const float* __restrict__ bk,
    const float* __restrict__ bv, const float* __restrict__ bs,
    float* __restrict__ qb, float* __restrict__ kb,
    float* __restrict__ vb, float* __restrict__ sb) {
    __shared__ float hs[32][128];
    int row0 = blockIdx.x * 32;
    int cglob = blockIdx.y * 64 + (threadIdx.x & 63);
    int mat = cglob >> 9;
    int wcol = cglob & 511;
    const float* W    = (mat == 0) ? Wq : (mat == 1) ? Wk : (mat == 2) ? Wv : Ws;
    const float* bias = (mat == 0) ? bq : (mat == 1) ? bk : (mat == 2) ? bv : bs;
    float* out        = (mat == 0) ? qb : (mat == 1) ? kb : (mat == 2) ? vb : sb;

    for (int idx = threadIdx.x; idx < 32 * 128; idx += 256) {
        int r = idx >> 7, c = idx & 127;
        int gr = row0 + r;
        hs[r][c] = (gr < NN) ? h[gr * 128 + c] : 0.f;
    }
    __syncthreads();
    int ty = threadIdx.x >> 6;  // 0..3
    float acc[8];
#pragma unroll
    for (int r = 0; r < 8; r++) acc[r] = 0.f;
    for (int k = 0; k < 128; k++) {
        float w = W[k * 512 + wcol];
#pragma unroll
        for (int r = 0; r < 8; r++) acc[r] += hs[ty + r * 4][k] * w;
    }
    float bvv = bias[wcol];
#pragma unroll
    for (int r = 0; r < 8; r++) {
        int gr = row0 + ty + r * 4;
        if (gr < NN) out[gr * 512 + wcol] = acc[r] + bvv;
    }
}

// ---------------- attention: one block per node, one wave per head ----------------
__global__ __launch_bounds__(256) void k_attn(const float* __restrict__ qb,
                                              const float* __restrict__ kb,
                                              const float* __restrict__ vb,
                                              const int* __restrict__ offs,
                                              const int* __restrict__ col,
                                              float* __restrict__ att) {
    int n = blockIdx.x;
    int head = threadIdx.x >> 6;
    int lane = threadIdx.x & 63;
    const float2 qv = ((const float2*)(qb + n * HCW + head * CH))[lane];
    int beg = offs[n], end = offs[n + 1];
    float m = -INFINITY, s = 0.f;
    float2 acc = {0.f, 0.f};
    const float scale = 0.08838834764831845f;  // 1/sqrt(128)
    for (int p = beg; p < end; ++p) {
        int sn = col[p];
        float2 kv = ((const float2*)(kb + sn * HCW + head * CH))[lane];
        float part = qv.x * kv.x + qv.y * kv.y;
#pragma unroll
        for (int off = 32; off; off >>= 1) part += __shfl_xor(part, off, 64);
        float logit = part * scale;
        float2 vv = ((const float2*)(vb + sn * HCW + head * CH))[lane];
        float mn = fmaxf(m, logit);
        float sc = __expf(m - mn);
        float w  = __expf(logit - mn);
        s = s * sc + w;
        acc.x = acc.x * sc + w * vv.x;
        acc.y = acc.y * sc + w * vv.y;
        m = mn;
    }
    float inv = (s > 0.f) ? 1.f / s : 0.f;
    float2 o = {acc.x * inv, acc.y * inv};
    ((float2*)(att + n * HCW + head * CH))[lane] = o;
}

// ---------------- beta gate + LN stats ----------------
__global__ __launch_bounds__(256) void k_beta(const float* __restrict__ att,
                                              const float* __restrict__ skip,
                                              const float* __restrict__ Wb,
                                              float* __restrict__ gated,
                                              float* __restrict__ stats) {
    int n = blockIdx.x;
    int t = threadIdx.x;
    float o0 = att[n * 512 + t], o1 = att[n * 512 + t + 256];
    float s0 = skip[n * 512 + t], s1 = skip[n * 512 + t + 256];
    float part = o0 * Wb[t] + o1 * Wb[t + 256]
               + s0 * Wb[512 + t] + s1 * Wb[512 + t + 256]
               + (o0 - s0) * Wb[1024 + t] + (o1 - s1) * Wb[1024 + t + 256];
    __shared__ float red[4];
#pragma unroll
    for (int off = 32; off; off >>= 1) part += __shfl_xor(part, off, 64);
    if ((t & 63) == 0) red[t >> 6] = part;
    __syncthreads();
    float tot = red[0] + red[1] + red[2] + red[3];
    float beta = 1.f / (1.f + __expf(-tot));
    float g0 = beta * s0 + (1.f - beta) * o0;
    float g1 = beta * s1 + (1.f - beta) * o1;
    gated[n * 512 + t] = g0;
    gated[n * 512 + t + 256] = g1;
    float ls = g0 + g1, lq = g0 * g0 + g1 * g1;
#pragma unroll
    for (int off = 32; off; off >>= 1) {
        ls += __shfl_xor(ls, off, 64);
        lq += __shfl_xor(lq, off, 64);
    }
    __shared__ float r2[8];
    if ((t & 63) == 0) { r2[t >> 6] = ls; r2[4 + (t >> 6)] = lq; }
    __syncthreads();
    if (t == 0) {
        atomicAdd(&stats[0], r2[0] + r2[1] + r2[2] + r2[3]);
        atomicAdd(&stats[1], r2[4] + r2[5] + r2[6] + r2[7]);
    }
}

// ---------------- LN apply + proj + residual + relu (h updated in place) ----------------
__global__ __launch_bounds__(256) void k_proj(const float* __restrict__ gated,
                                              const float* __restrict__ Wp,
                                              const float* __restrict__ bp,
                                              const float* __restrict__ lw,
                                              const float* __restrict__ lb,
                                              const float* __restrict__ stats,
                                              float* __restrict__ h) {
    __shared__ float ls[32][128];
    int row0 = blockIdx.x * 32;
    int tx = threadIdx.x & 127;
    int ty = threadIdx.x >> 7;  // 0..1
    const float invM = 1.f / (NN * 512.f);
    float mean = stats[0] * invM;
    float ms = stats[1] * invM - mean * mean;
    float rstd = 1.f / (sqrtf(fmaxf(ms, 0.f)) + LN_EPS);
    float acc[16];
#pragma unroll
    for (int r = 0; r < 16; r++) acc[r] = 0.f;
    for (int k0 = 0; k0 < 512; k0 += 128) {
        __syncthreads();
        for (int idx = threadIdx.x; idx < 32 * 128; idx += 256) {
            int r = idx >> 7, c = idx & 127;
            int gr = row0 + r, gc = k0 + c;
            float g = (gr < NN) ? gated[gr * 512 + gc] : 0.f;
            ls[r][c] = (g - mean) * rstd * lw[gc] + lb[gc];
        }
        __syncthreads();
        for (int kk = 0; kk < 128; kk++) {
            float w = Wp[(k0 + kk) * 128 + tx];
#pragma unroll
            for (int r = 0; r < 16; r++) acc[r] += ls[ty + r * 2][kk] * w;
        }
    }
    float bb = bp[tx];
#pragma unroll
    for (int r = 0; r < 16; r++) {
        int gr = row0 + ty + r * 2;
        if (gr < NN) {
            float hv = h[gr * 128 + tx];
            float o = acc[r] + bb + hv;
            h[gr * 128 + tx] = fmaxf(o, 0.f);
        }
    }
}

// ---------------- output projection ----------------
__global__ void k_out(const float* __restrict__ h, const float* __restrict__ W,
                      const float* __restrict__ b, float* __restrict__ out) {
    int i = blockIdx.x * blockDim.x + threadIdx.x;
    if (i >= NN * 5) return;
    int n = i / 5, j = i % 5;
    float acc = b[j];
    for (int k = 0; k < 128; k++) acc += h[n * 128 + k] * W[k * 5 + j];
    out[i] = acc;
}

extern "C" void kernel_launch(void* const* d_in, const int* in_sizes, int n_in,
                              void* d_out, int out_size, void* d_ws, size_t ws_size,
                              hipStream_t stream) {
    const float* x     = (const float*)d_in[0];
    const int* ei      = (const int*)d_in[1];
    const float* W_in  = (const float*)d_in[2];
    const float* b_in  = (const float*)d_in[3];
    const float* W_out = (const float*)d_in[4];
    const float* b_out = (const float*)d_in[5];
    const float* Wq    = (const float*)d_in[6];
    const float* bq    = (const float*)d_in[7];
    const float* Wk    = (const float*)d_in[8];
    const float* bk    = (const float*)d_in[9];
    const float* Wv    = (const float*)d_in[10];
    const float* bv    = (const float*)d_in[11];
    const float* Wsk   = (const float*)d_in[12];
    const float* bsk   = (const float*)d_in[13];
    const float* Wbeta = (const float*)d_in[14];
    const float* ln_w  = (const float*)d_in[15];
    const float* ln_b  = (const float*)d_in[16];
    const float* Wproj = (const float*)d_in[17];
    const float* bproj = (const float*)d_in[18];
    float* out = (float*)d_out;

    // workspace layout
    float* h   = (float*)d_ws;                 // N*128
    float* z   = h + NN * 128;                 // 4 * N*512 (q,k,v,skip)
    float* qb  = z;
    float* kb  = z + (size_t)NN * 512;
    float* vb  = z + (size_t)2 * NN * 512;
    float* sb  = z + (size_t)3 * NN * 512;
    float* att = z + (size_t)4 * NN * 512;     // N*512
    float* stats = att + (size_t)NN * 512;     // 16 floats (2 per layer)
    int* offs = (int*)(stats + 16);            // N+1
    int* cnt  = offs + (NN + 1);               // N
    int* fill = cnt + NN;                      // N
    int* col  = fill + NN;                     // E
    float* gated = qb;                         // alias q region (dead after attention)

    const int* src = ei;
    const int* dst = ei + NE;

    k_init<<<(NN + 255) / 256, 256, 0, stream>>>(cnt, fill, stats);
    k_count<<<(NE + 255) / 256, 256, 0, stream>>>(dst, cnt);
    k_scan<<<1, 1024, 0, stream>>>(cnt, offs);
    k_fill<<<(NE + 255) / 256, 256, 0, stream>>>(src, dst, offs, fill, col);
    k_inproj<<<NN, 128, 0, stream>>>(x, W_in, b_in, h);

    for (int l = 0; l < NLAYERS; ++l) {
        const float* Wq_ = Wq + (size_t)l * 128 * 512;
        const float* Wk_ = Wk + (size_t)l * 128 * 512;
        const float* Wv_ = Wv + (size_t)l * 128 * 512;
        const float* Ws_ = Wsk + (size_t)l * 128 * 512;
        const float* bq_ = bq + l * 512;
        const float* bk_ = bk + l * 512;
        const float* bv_ = bv + l * 512;
        const float* bs_ = bsk + l * 512;
        const float* Wb_ = Wbeta + (size_t)l * 1536;
        const float* lw_ = ln_w + l * 512;
        const float* lb_ = ln_b + l * 512;
        const float* Wp_ = Wproj + (size_t)l * 512 * 128;
        const float* bp_ = bproj + l * 128;
        float* st = stats + 2 * l;

        dim3 g1((NN + 31) / 32, 32);
        k_qkvs<<<g1, 256, 0, stream>>>(h, Wq_, Wk_, Wv_, Ws_, bq_, bk_, bv_, bs_,
                                       qb, kb, vb, sb);
        k_attn<<<NN, 256, 0, stream>>>(qb, kb, vb, offs, col, att);
        k_beta<<<NN, 256, 0, stream>>>(att, sb, Wb_, gated, st);
        k_proj<<<(NN + 31) / 32, 256, 0, stream>>>(gated, Wp_, bp_, lw_, lb_, st, h);
    }
    k_out<<<(NN * 5 + 255) / 256, 256, 0, stream>>>(h, W_out, b_out, out);
}

// Round 2
// 1701.778 us; speedup vs baseline: 1.5961x; 1.5961x over previous
//
#include <hip/hip_runtime.h>
#include <math.h>

#define NN 10000
#define NE 160000
#define HCW 512
#define CH 128
#define NLAYERS 4
#define LN_EPS 1e-5f

typedef short bf16x8 __attribute__((ext_vector_type(8)));
typedef float f32x4 __attribute__((ext_vector_type(4)));

__device__ inline unsigned short f2bf(float f) {
    union { float f; unsigned int u; } x; x.f = f;
    unsigned int u = x.u;
    return (unsigned short)((u + 0x7FFFu + ((u >> 16) & 1u)) >> 16);
}
__device__ inline float bf2f(unsigned short s) {
    union { unsigned int u; float f; } x; x.u = ((unsigned int)s) << 16;
    return x.f;
}

// ---------------- CSR build ----------------
__global__ void k_init(int* cnt, int* fill, float* stats) {
    int i = blockIdx.x * blockDim.x + threadIdx.x;
    if (i < NN) { cnt[i] = 0; fill[i] = 0; }
    if (i < 16) stats[i] = 0.f;
}

__global__ void k_count(const int* __restrict__ dst, int* __restrict__ cnt) {
    int e = blockIdx.x * blockDim.x + threadIdx.x;
    if (e < NE) atomicAdd(&cnt[dst[e]], 1);
}

__global__ __launch_bounds__(1024) void k_scan(const int* __restrict__ cnt, int* __restrict__ offs) {
    __shared__ int sh[1024];
    __shared__ int carry;
    if (threadIdx.x == 0) carry = 0;
    __syncthreads();
    for (int base = 0; base < NN; base += 1024) {
        int i = base + threadIdx.x;
        int v = (i < NN) ? cnt[i] : 0;
        sh[threadIdx.x] = v;
        __syncthreads();
        for (int off = 1; off < 1024; off <<= 1) {
            int t = (threadIdx.x >= off) ? sh[threadIdx.x - off] : 0;
            __syncthreads();
            sh[threadIdx.x] += t;
            __syncthreads();
        }
        int incl = sh[threadIdx.x];
        if (i < NN) offs[i] = carry + incl - v;
        __syncthreads();
        if (threadIdx.x == 1023) carry += sh[1023];
        __syncthreads();
    }
    if (threadIdx.x == 0) offs[NN] = carry;
}

__global__ void k_fill(const int* __restrict__ src, const int* __restrict__ dst,
                       const int* __restrict__ offs, int* __restrict__ fill,
                       int* __restrict__ col) {
    int e = blockIdx.x * blockDim.x + threadIdx.x;
    if (e < NE) {
        int d = dst[e];
        int p = offs[d] + atomicAdd(&fill[d], 1);
        col[p] = src[e];
    }
}

// ---------------- weight convert: fp32 -> bf16, [K][N] -> [N][K] ----------------
__global__ void k_wconv(const float* __restrict__ Wq, const float* __restrict__ Wk,
                        const float* __restrict__ Wv, const float* __restrict__ Ws,
                        const float* __restrict__ Wp,
                        unsigned short* __restrict__ wt_qkvs,   // [L][2048][128]
                        unsigned short* __restrict__ wpt) {     // [L][128][512]
    int id = blockIdx.x * blockDim.x + threadIdx.x;
    if (id < NLAYERS * 2048 * 128) {
        int l = id >> 18;
        int rem = id & 262143;
        int n = rem >> 7, k = rem & 127;
        int mat = n >> 9, wcol = n & 511;
        const float* W = (mat == 0) ? Wq : (mat == 1) ? Wk : (mat == 2) ? Wv : Ws;
        wt_qkvs[id] = f2bf(W[(size_t)l * 65536 + k * 512 + wcol]);
    } else if (id < NLAYERS * 2048 * 128 + NLAYERS * 128 * 512) {
        int id2 = id - NLAYERS * 2048 * 128;
        int l = id2 >> 16;
        int rem = id2 & 65535;
        int n = rem >> 9, k = rem & 511;
        wpt[(size_t)l * 65536 + n * 512 + k] = f2bf(Wp[(size_t)l * 65536 + k * 128 + n]);
    }
}

// ---------------- input projection ----------------
__global__ __launch_bounds__(128) void k_inproj(const float* __restrict__ x,
                                                const float* __restrict__ W,
                                                const float* __restrict__ b,
                                                float* __restrict__ h,
                                                unsigned short* __restrict__ h_bf) {
    int n = blockIdx.x;
    int j = threadIdx.x;
    float acc = b[j];
#pragma unroll
    for (int i = 0; i < 15; i++) acc += x[n * 15 + i] * W[i * 128 + j];
    h[n * 128 + j] = acc;
    h_bf[n * 128 + j] = f2bf(acc);
}

// ---------------- fused qkv+skip MFMA GEMM: [N,128]bf16 @ [128,2048]bf16 ----------------
// q,skip -> fp32 out; k,v -> bf16 out
__global__ __launch_bounds__(256) void k_qkvs_mfma(
    const unsigned short* __restrict__ h_bf,   // [NN][128]
    const unsigned short* __restrict__ Wt,     // [2048][128] layer slice
    const float* __restrict__ bq, const float* __restrict__ bk,
    const float* __restrict__ bv, const float* __restrict__ bs,
    float* __restrict__ qb, unsigned short* __restrict__ kb16,
    unsigned short* __restrict__ vb16, float* __restrict__ sb) {
    __shared__ unsigned short As[128 * 128];
    __shared__ unsigned short Bs[128 * 128];
    int row0 = blockIdx.x * 128;
    int n0 = blockIdx.y * 128;
    int t = threadIdx.x;
    // stage A (swizzled 16B chunks)
#pragma unroll
    for (int i = 0; i < 8; i++) {
        int c = t + i * 256;
        int r = c >> 4, cc = c & 15;
        int gr = row0 + r;
        uint4 v = make_uint4(0, 0, 0, 0);
        if (gr < NN) v = *(const uint4*)(h_bf + (size_t)gr * 128 + cc * 8);
        int sc = (r << 4) | (cc ^ (r & 7));
        *(uint4*)(As + sc * 8) = v;
    }
    // stage B
#pragma unroll
    for (int i = 0; i < 8; i++) {
        int c = t + i * 256;
        int r = c >> 4, cc = c & 15;
        uint4 v = *(const uint4*)(Wt + (size_t)(n0 + r) * 128 + cc * 8);
        int sc = (r << 4) | (cc ^ (r & 7));
        *(uint4*)(Bs + sc * 8) = v;
    }
    __syncthreads();
    int wave = t >> 6, lane = t & 63;
    int wr = (wave >> 1) * 64, wc = (wave & 1) * 64;
    int lr = lane & 15, lk = lane >> 4;
    f32x4 acc[4][4] = {};
#pragma unroll
    for (int ks = 0; ks < 4; ks++) {
        bf16x8 a[4], b[4];
#pragma unroll
        for (int mi = 0; mi < 4; mi++) {
            int r = wr + mi * 16 + lr;
            int cc = (ks * 4 + lk) ^ (r & 7);
            a[mi] = *(const bf16x8*)(As + (((r << 4) | cc) * 8));
        }
#pragma unroll
        for (int ni = 0; ni < 4; ni++) {
            int r = wc + ni * 16 + lr;
            int cc = (ks * 4 + lk) ^ (r & 7);
            b[ni] = *(const bf16x8*)(Bs + (((r << 4) | cc) * 8));
        }
#pragma unroll
        for (int mi = 0; mi < 4; mi++)
#pragma unroll
            for (int ni = 0; ni < 4; ni++)
                acc[mi][ni] = __builtin_amdgcn_mfma_f32_16x16x32_bf16(a[mi], b[ni], acc[mi][ni], 0, 0, 0);
    }
    // epilogue
#pragma unroll
    for (int ni = 0; ni < 4; ni++) {
        int gc = n0 + wc + ni * 16 + lr;
        int mat = gc >> 9, wcol = gc & 511;
        float bias = ((mat == 0) ? bq : (mat == 1) ? bk : (mat == 2) ? bv : bs)[wcol];
#pragma unroll
        for (int mi = 0; mi < 4; mi++) {
            int gr0 = row0 + wr + mi * 16 + 4 * lk;
#pragma unroll
            for (int r = 0; r < 4; r++) {
                int grr = gr0 + r;
                if (grr < NN) {
                    float val = acc[mi][ni][r] + bias;
                    if (mat == 0)      qb[(size_t)grr * 512 + wcol] = val;
                    else if (mat == 3) sb[(size_t)grr * 512 + wcol] = val;
                    else if (mat == 1) kb16[(size_t)grr * 512 + wcol] = f2bf(val);
                    else               vb16[(size_t)grr * 512 + wcol] = f2bf(val);
                }
            }
        }
    }
}

// ---------------- attention: one block per node, one wave per head ----------------
__global__ __launch_bounds__(256) void k_attn(const float* __restrict__ qb,
                                              const unsigned short* __restrict__ kb16,
                                              const unsigned short* __restrict__ vb16,
                                              const int* __restrict__ offs,
                                              const int* __restrict__ col,
                                              float* __restrict__ att) {
    int n = blockIdx.x;
    int head = threadIdx.x >> 6;
    int lane = threadIdx.x & 63;
    const float2 qv = ((const float2*)(qb + (size_t)n * HCW + head * CH))[lane];
    int beg = offs[n], end = offs[n + 1];
    float m = -INFINITY, s = 0.f;
    float2 acc = {0.f, 0.f};
    const float scale = 0.08838834764831845f;  // 1/sqrt(128)
    for (int p = beg; p < end; ++p) {
        int sn = col[p];
        unsigned int kk = *(const unsigned int*)(kb16 + (size_t)sn * HCW + head * CH + lane * 2);
        float kx = bf2f((unsigned short)(kk & 0xffff));
        float ky = bf2f((unsigned short)(kk >> 16));
        float part = qv.x * kx + qv.y * ky;
#pragma unroll
        for (int off = 32; off; off >>= 1) part += __shfl_xor(part, off, 64);
        float logit = part * scale;
        unsigned int vv = *(const unsigned int*)(vb16 + (size_t)sn * HCW + head * CH + lane * 2);
        float vx = bf2f((unsigned short)(vv & 0xffff));
        float vy = bf2f((unsigned short)(vv >> 16));
        float mn = fmaxf(m, logit);
        float sc = __expf(m - mn);
        float w = __expf(logit - mn);
        s = s * sc + w;
        acc.x = acc.x * sc + w * vx;
        acc.y = acc.y * sc + w * vy;
        m = mn;
    }
    float inv = (s > 0.f) ? 1.f / s : 0.f;
    float2 o = {acc.x * inv, acc.y * inv};
    ((float2*)(att + (size_t)n * HCW + head * CH))[lane] = o;
}

// ---------------- beta gate + LN stats ----------------
__global__ __launch_bounds__(256) void k_beta(const float* __restrict__ att,
                                              const float* __restrict__ skip,
                                              const float* __restrict__ Wb,
                                              float* __restrict__ gated,
                                              float* __restrict__ stats) {
    int n = blockIdx.x;
    int t = threadIdx.x;
    float o0 = att[(size_t)n * 512 + t], o1 = att[(size_t)n * 512 + t + 256];
    float s0 = skip[(size_t)n * 512 + t], s1 = skip[(size_t)n * 512 + t + 256];
    float part = o0 * Wb[t] + o1 * Wb[t + 256]
               + s0 * Wb[512 + t] + s1 * Wb[512 + t + 256]
               + (o0 - s0) * Wb[1024 + t] + (o1 - s1) * Wb[1024 + t + 256];
    __shared__ float red[4];
#pragma unroll
    for (int off = 32; off; off >>= 1) part += __shfl_xor(part, off, 64);
    if ((t & 63) == 0) red[t >> 6] = part;
    __syncthreads();
    float tot = red[0] + red[1] + red[2] + red[3];
    float beta = 1.f / (1.f + __expf(-tot));
    float g0 = beta * s0 + (1.f - beta) * o0;
    float g1 = beta * s1 + (1.f - beta) * o1;
    gated[(size_t)n * 512 + t] = g0;
    gated[(size_t)n * 512 + t + 256] = g1;
    float ls = g0 + g1, lq = g0 * g0 + g1 * g1;
#pragma unroll
    for (int off = 32; off; off >>= 1) {
        ls += __shfl_xor(ls, off, 64);
        lq += __shfl_xor(lq, off, 64);
    }
    __shared__ float r2[8];
    if ((t & 63) == 0) { r2[t >> 6] = ls; r2[4 + (t >> 6)] = lq; }
    __syncthreads();
    if (t == 0) {
        atomicAdd(&stats[0], r2[0] + r2[1] + r2[2] + r2[3]);
        atomicAdd(&stats[1], r2[4] + r2[5] + r2[6] + r2[7]);
    }
}

// ---------------- LN + proj MFMA + residual + relu ----------------
__global__ __launch_bounds__(256) void k_proj_mfma(
    const float* __restrict__ gated,           // [NN][512]
    const unsigned short* __restrict__ Wpt,    // [128][512] layer slice
    const float* __restrict__ bp,
    const float* __restrict__ lw, const float* __restrict__ lb,
    const float* __restrict__ stats,
    float* __restrict__ h, unsigned short* __restrict__ h_bf) {
    __shared__ unsigned short As[128 * 128];
    __shared__ unsigned short Bs[128 * 128];
    int row0 = blockIdx.x * 128;
    int t = threadIdx.x;
    const float invM = 1.f / (NN * 512.f);
    float mean = stats[0] * invM;
    float ms = stats[1] * invM - mean * mean;
    float rstd = 1.f / (sqrtf(fmaxf(ms, 0.f)) + LN_EPS);
    int wave = t >> 6, lane = t & 63;
    int wr = (wave >> 1) * 64, wc = (wave & 1) * 64;
    int lr = lane & 15, lk = lane >> 4;
    f32x4 acc[4][4] = {};
    for (int kc = 0; kc < 4; kc++) {
        __syncthreads();
#pragma unroll
        for (int i = 0; i < 8; i++) {
            int c = t + i * 256;
            int r = c >> 4, cc = c & 15;
            int gr = row0 + r;
            int gk = kc * 128 + cc * 8;
            unsigned short u[8];
            if (gr < NN) {
                const float* g = gated + (size_t)gr * 512 + gk;
#pragma unroll
                for (int j = 0; j < 8; j++) {
                    float v = (g[j] - mean) * rstd * lw[gk + j] + lb[gk + j];
                    u[j] = f2bf(v);
                }
            } else {
#pragma unroll
                for (int j = 0; j < 8; j++) u[j] = 0;
            }
            int sc = (r << 4) | (cc ^ (r & 7));
            *(uint4*)(As + sc * 8) = *(uint4*)u;
        }
#pragma unroll
        for (int i = 0; i < 8; i++) {
            int c = t + i * 256;
            int r = c >> 4, cc = c & 15;
            uint4 v = *(const uint4*)(Wpt + (size_t)r * 512 + kc * 128 + cc * 8);
            int sc = (r << 4) | (cc ^ (r & 7));
            *(uint4*)(Bs + sc * 8) = v;
        }
        __syncthreads();
#pragma unroll
        for (int ks = 0; ks < 4; ks++) {
            bf16x8 a[4], b[4];
#pragma unroll
            for (int mi = 0; mi < 4; mi++) {
                int r = wr + mi * 16 + lr;
                int cc = (ks * 4 + lk) ^ (r & 7);
                a[mi] = *(const bf16x8*)(As + (((r << 4) | cc) * 8));
            }
#pragma unroll
            for (int ni = 0; ni < 4; ni++) {
                int r = wc + ni * 16 + lr;
                int cc = (ks * 4 + lk) ^ (r & 7);
                b[ni] = *(const bf16x8*)(Bs + (((r << 4) | cc) * 8));
            }
#pragma unroll
            for (int mi = 0; mi < 4; mi++)
#pragma unroll
                for (int ni = 0; ni < 4; ni++)
                    acc[mi][ni] = __builtin_amdgcn_mfma_f32_16x16x32_bf16(a[mi], b[ni], acc[mi][ni], 0, 0, 0);
        }
    }
#pragma unroll
    for (int ni = 0; ni < 4; ni++) {
        int gc = wc + ni * 16 + lr;  // 0..127
        float bias = bp[gc];
#pragma unroll
        for (int mi = 0; mi < 4; mi++) {
            int gr0 = row0 + wr + mi * 16 + 4 * lk;
#pragma unroll
            for (int r = 0; r < 4; r++) {
                int grr = gr0 + r;
                if (grr < NN) {
                    float o = acc[mi][ni][r] + bias + h[(size_t)grr * 128 + gc];
                    o = fmaxf(o, 0.f);
                    h[(size_t)grr * 128 + gc] = o;
                    h_bf[(size_t)grr * 128 + gc] = f2bf(o);
                }
            }
        }
    }
}

// ---------------- output projection ----------------
__global__ void k_out(const float* __restrict__ h, const float* __restrict__ W,
                      const float* __restrict__ b, float* __restrict__ out) {
    int i = blockIdx.x * blockDim.x + threadIdx.x;
    if (i >= NN * 5) return;
    int n = i / 5, j = i % 5;
    float acc = b[j];
    for (int k = 0; k < 128; k++) acc += h[(size_t)n * 128 + k] * W[k * 5 + j];
    out[i] = acc;
}

extern "C" void kernel_launch(void* const* d_in, const int* in_sizes, int n_in,
                              void* d_out, int out_size, void* d_ws, size_t ws_size,
                              hipStream_t stream) {
    const float* x     = (const float*)d_in[0];
    const int* ei      = (const int*)d_in[1];
    const float* W_in  = (const float*)d_in[2];
    const float* b_in  = (const float*)d_in[3];
    const float* W_out = (const float*)d_in[4];
    const float* b_out = (const float*)d_in[5];
    const float* Wq    = (const float*)d_in[6];
    const float* bq    = (const float*)d_in[7];
    const float* Wk    = (const float*)d_in[8];
    const float* bk    = (const float*)d_in[9];
    const float* Wv    = (const float*)d_in[10];
    const float* bv    = (const float*)d_in[11];
    const float* Wsk   = (const float*)d_in[12];
    const float* bsk   = (const float*)d_in[13];
    const float* Wbeta = (const float*)d_in[14];
    const float* ln_w  = (const float*)d_in[15];
    const float* ln_b  = (const float*)d_in[16];
    const float* Wproj = (const float*)d_in[17];
    const float* bproj = (const float*)d_in[18];
    float* out = (float*)d_out;

    // workspace layout (floats/ints then 16B-aligned bf16 regions)
    float* h     = (float*)d_ws;                    // N*128
    float* qb    = h + (size_t)NN * 128;            // N*512
    float* sb    = qb + (size_t)NN * 512;           // N*512
    float* att   = sb + (size_t)NN * 512;           // N*512
    float* stats = att + (size_t)NN * 512;          // 16
    int* offs = (int*)(stats + 16);                 // N+1
    int* cnt  = offs + (NN + 1);
    int* fill = cnt + NN;
    int* col  = fill + NN;                          // E
    unsigned short* h_bf = (unsigned short*)(((uintptr_t)(col + NE) + 15) & ~(uintptr_t)15);
    unsigned short* kb16 = h_bf + (size_t)NN * 128;
    unsigned short* vb16 = kb16 + (size_t)NN * 512;
    unsigned short* wt_qkvs = vb16 + (size_t)NN * 512;     // L*2048*128
    unsigned short* wpt = wt_qkvs + (size_t)NLAYERS * 2048 * 128;  // L*128*512
    float* gated = qb;  // alias (q dead after attention)

    const int* src = ei;
    const int* dst = ei + NE;

    k_init<<<(NN + 255) / 256, 256, 0, stream>>>(cnt, fill, stats);
    k_count<<<(NE + 255) / 256, 256, 0, stream>>>(dst, cnt);
    k_scan<<<1, 1024, 0, stream>>>(cnt, offs);
    k_fill<<<(NE + 255) / 256, 256, 0, stream>>>(src, dst, offs, fill, col);
    {
        int tot = NLAYERS * 2048 * 128 + NLAYERS * 128 * 512;
        k_wconv<<<(tot + 255) / 256, 256, 0, stream>>>(Wq, Wk, Wv, Wsk, Wproj, wt_qkvs, wpt);
    }
    k_inproj<<<NN, 128, 0, stream>>>(x, W_in, b_in, h, h_bf);

    for (int l = 0; l < NLAYERS; ++l) {
        const unsigned short* Wt_ = wt_qkvs + (size_t)l * 2048 * 128;
        const unsigned short* Wp_ = wpt + (size_t)l * 128 * 512;
        const float* bq_ = bq + l * 512;
        const float* bk_ = bk + l * 512;
        const float* bv_ = bv + l * 512;
        const float* bs_ = bsk + l * 512;
        const float* Wb_ = Wbeta + (size_t)l * 1536;
        const float* lw_ = ln_w + l * 512;
        const float* lb_ = ln_b + l * 512;
        const float* bp_ = bproj + l * 128;
        float* st = stats + 2 * l;

        dim3 g1((NN + 127) / 128, 16);
        k_qkvs_mfma<<<g1, 256, 0, stream>>>(h_bf, Wt_, bq_, bk_, bv_, bs_,
                                            qb, kb16, vb16, sb);
        k_attn<<<NN, 256, 0, stream>>>(qb, kb16, vb16, offs, col, att);
        k_beta<<<NN, 256, 0, stream>>>(att, sb, Wb_, gated, st);
        k_proj_mfma<<<(NN + 127) / 128, 256, 0, stream>>>(gated, Wp_, bp_, lw_, lb_, st, h, h_bf);
    }
    k_out<<<(NN * 5 + 255) / 256, 256, 0, stream>>>(h, W_out, b_out, out);
}

// Round 3
// 716.097 us; speedup vs baseline: 3.7930x; 2.3765x over previous
//
#include <hip/hip_runtime.h>
#include <math.h>

#define NN 10000
#define NE 160000
#define HCW 512
#define CH 128
#define NLAYERS 4
#define LN_EPS 1e-5f
#define NBUCK 128   // LN-stat atomic buckets, each on its own 64B line

typedef short bf16x8 __attribute__((ext_vector_type(8)));
typedef float f32x4 __attribute__((ext_vector_type(4)));

__device__ inline unsigned short f2bf(float f) {
    union { float f; unsigned int u; } x; x.f = f;
    unsigned int u = x.u;
    return (unsigned short)((u + 0x7FFFu + ((u >> 16) & 1u)) >> 16);
}
__device__ inline float bf2f(unsigned short s) {
    union { unsigned int u; float f; } x; x.u = ((unsigned int)s) << 16;
    return x.f;
}

// ---------------- CSR build ----------------
__global__ void k_init(int* cnt, int* fill, float* stats) {
    int i = blockIdx.x * blockDim.x + threadIdx.x;
    if (i < NN) { cnt[i] = 0; fill[i] = 0; }
    if (i < NLAYERS * NBUCK * 16) stats[i] = 0.f;
}

__global__ void k_count(const int* __restrict__ dst, int* __restrict__ cnt) {
    int e = blockIdx.x * blockDim.x + threadIdx.x;
    if (e < NE) atomicAdd(&cnt[dst[e]], 1);
}

__global__ __launch_bounds__(1024) void k_scan(const int* __restrict__ cnt, int* __restrict__ offs) {
    __shared__ int sh[1024];
    __shared__ int carry;
    if (threadIdx.x == 0) carry = 0;
    __syncthreads();
    for (int base = 0; base < NN; base += 1024) {
        int i = base + threadIdx.x;
        int v = (i < NN) ? cnt[i] : 0;
        sh[threadIdx.x] = v;
        __syncthreads();
        for (int off = 1; off < 1024; off <<= 1) {
            int t = (threadIdx.x >= off) ? sh[threadIdx.x - off] : 0;
            __syncthreads();
            sh[threadIdx.x] += t;
            __syncthreads();
        }
        int incl = sh[threadIdx.x];
        if (i < NN) offs[i] = carry + incl - v;
        __syncthreads();
        if (threadIdx.x == 1023) carry += sh[1023];
        __syncthreads();
    }
    if (threadIdx.x == 0) offs[NN] = carry;
}

__global__ void k_fill(const int* __restrict__ src, const int* __restrict__ dst,
                       const int* __restrict__ offs, int* __restrict__ fill,
                       int* __restrict__ col) {
    int e = blockIdx.x * blockDim.x + threadIdx.x;
    if (e < NE) {
        int d = dst[e];
        int p = offs[d] + atomicAdd(&fill[d], 1);
        col[p] = src[e];
    }
}

// ---------------- weight convert: fp32 -> bf16, [K][N] -> [N][K] ----------------
__global__ void k_wconv(const float* __restrict__ Wq, const float* __restrict__ Wk,
                        const float* __restrict__ Wv, const float* __restrict__ Ws,
                        const float* __restrict__ Wp,
                        unsigned short* __restrict__ wt_qkvs,   // [L][2048][128]
                        unsigned short* __restrict__ wpt) {     // [L][128][512]
    int id = blockIdx.x * blockDim.x + threadIdx.x;
    if (id < NLAYERS * 2048 * 128) {
        int l = id >> 18;
        int rem = id & 262143;
        int n = rem >> 7, k = rem & 127;
        int mat = n >> 9, wcol = n & 511;
        const float* W = (mat == 0) ? Wq : (mat == 1) ? Wk : (mat == 2) ? Wv : Ws;
        wt_qkvs[id] = f2bf(W[(size_t)l * 65536 + k * 512 + wcol]);
    } else if (id < NLAYERS * 2048 * 128 + NLAYERS * 128 * 512) {
        int id2 = id - NLAYERS * 2048 * 128;
        int l = id2 >> 16;
        int rem = id2 & 65535;
        int n = rem >> 9, k = rem & 511;
        wpt[(size_t)l * 65536 + n * 512 + k] = f2bf(Wp[(size_t)l * 65536 + k * 128 + n]);
    }
}

// ---------------- input projection ----------------
__global__ __launch_bounds__(128) void k_inproj(const float* __restrict__ x,
                                                const float* __restrict__ W,
                                                const float* __restrict__ b,
                                                float* __restrict__ h,
                                                unsigned short* __restrict__ h_bf) {
    int n = blockIdx.x;
    int j = threadIdx.x;
    float acc = b[j];
#pragma unroll
    for (int i = 0; i < 15; i++) acc += x[n * 15 + i] * W[i * 128 + j];
    h[n * 128 + j] = acc;
    h_bf[n * 128 + j] = f2bf(acc);
}

// ---------------- fused qkv+skip MFMA GEMM ----------------
__global__ __launch_bounds__(256) void k_qkvs_mfma(
    const unsigned short* __restrict__ h_bf,   // [NN][128]
    const unsigned short* __restrict__ Wt,     // [2048][128] layer slice
    const float* __restrict__ bq, const float* __restrict__ bk,
    const float* __restrict__ bv, const float* __restrict__ bs,
    float* __restrict__ qb, unsigned short* __restrict__ kb16,
    unsigned short* __restrict__ vb16, float* __restrict__ sb) {
    __shared__ unsigned short As[128 * 128];
    __shared__ unsigned short Bs[128 * 128];
    int row0 = blockIdx.x * 128;
    int n0 = blockIdx.y * 128;
    int t = threadIdx.x;
#pragma unroll
    for (int i = 0; i < 8; i++) {
        int c = t + i * 256;
        int r = c >> 4, cc = c & 15;
        int gr = row0 + r;
        uint4 v = make_uint4(0, 0, 0, 0);
        if (gr < NN) v = *(const uint4*)(h_bf + (size_t)gr * 128 + cc * 8);
        int sc = (r << 4) | (cc ^ (r & 7));
        *(uint4*)(As + sc * 8) = v;
    }
#pragma unroll
    for (int i = 0; i < 8; i++) {
        int c = t + i * 256;
        int r = c >> 4, cc = c & 15;
        uint4 v = *(const uint4*)(Wt + (size_t)(n0 + r) * 128 + cc * 8);
        int sc = (r << 4) | (cc ^ (r & 7));
        *(uint4*)(Bs + sc * 8) = v;
    }
    __syncthreads();
    int wave = t >> 6, lane = t & 63;
    int wr = (wave >> 1) * 64, wc = (wave & 1) * 64;
    int lr = lane & 15, lk = lane >> 4;
    f32x4 acc[4][4] = {};
#pragma unroll
    for (int ks = 0; ks < 4; ks++) {
        bf16x8 a[4], b[4];
#pragma unroll
        for (int mi = 0; mi < 4; mi++) {
            int r = wr + mi * 16 + lr;
            int cc = (ks * 4 + lk) ^ (r & 7);
            a[mi] = *(const bf16x8*)(As + (((r << 4) | cc) * 8));
        }
#pragma unroll
        for (int ni = 0; ni < 4; ni++) {
            int r = wc + ni * 16 + lr;
            int cc = (ks * 4 + lk) ^ (r & 7);
            b[ni] = *(const bf16x8*)(Bs + (((r << 4) | cc) * 8));
        }
#pragma unroll
        for (int mi = 0; mi < 4; mi++)
#pragma unroll
            for (int ni = 0; ni < 4; ni++)
                acc[mi][ni] = __builtin_amdgcn_mfma_f32_16x16x32_bf16(a[mi], b[ni], acc[mi][ni], 0, 0, 0);
    }
#pragma unroll
    for (int ni = 0; ni < 4; ni++) {
        int gc = n0 + wc + ni * 16 + lr;
        int mat = gc >> 9, wcol = gc & 511;
        float bias = ((mat == 0) ? bq : (mat == 1) ? bk : (mat == 2) ? bv : bs)[wcol];
#pragma unroll
        for (int mi = 0; mi < 4; mi++) {
            int gr0 = row0 + wr + mi * 16 + 4 * lk;
#pragma unroll
            for (int r = 0; r < 4; r++) {
                int grr = gr0 + r;
                if (grr < NN) {
                    float val = acc[mi][ni][r] + bias;
                    if (mat == 0)      qb[(size_t)grr * 512 + wcol] = val;
                    else if (mat == 3) sb[(size_t)grr * 512 + wcol] = val;
                    else if (mat == 1) kb16[(size_t)grr * 512 + wcol] = f2bf(val);
                    else               vb16[(size_t)grr * 512 + wcol] = f2bf(val);
                }
            }
        }
    }
}

// ---------------- fused attention + beta gate + LN stats ----------------
// one block per node, one wave per head; writes gated (aliases qb: block n
// only touches row n, q row read before write)
__global__ __launch_bounds__(256) void k_attn_beta(
    const float* __restrict__ qb,
    const unsigned short* __restrict__ kb16,
    const unsigned short* __restrict__ vb16,
    const float* __restrict__ skip,
    const float* __restrict__ Wb,
    const int* __restrict__ offs, const int* __restrict__ col,
    float* __restrict__ gated, float* __restrict__ stats) {
    int n = blockIdx.x;
    int head = threadIdx.x >> 6;
    int lane = threadIdx.x & 63;
    const float2 qv = ((const float2*)(qb + (size_t)n * HCW + head * CH))[lane];
    int beg = offs[n], end = offs[n + 1];
    float m = -INFINITY, s = 0.f;
    float2 acc = {0.f, 0.f};
    const float scale = 0.08838834764831845f;  // 1/sqrt(128)
    for (int p = beg; p < end; ++p) {
        int sn = col[p];
        unsigned int kk = *(const unsigned int*)(kb16 + (size_t)sn * HCW + head * CH + lane * 2);
        float kx = bf2f((unsigned short)(kk & 0xffff));
        float ky = bf2f((unsigned short)(kk >> 16));
        float part = qv.x * kx + qv.y * ky;
#pragma unroll
        for (int off = 32; off; off >>= 1) part += __shfl_xor(part, off, 64);
        float logit = part * scale;
        unsigned int vv = *(const unsigned int*)(vb16 + (size_t)sn * HCW + head * CH + lane * 2);
        float vx = bf2f((unsigned short)(vv & 0xffff));
        float vy = bf2f((unsigned short)(vv >> 16));
        float mn = fmaxf(m, logit);
        float sc = __expf(m - mn);
        float w = __expf(logit - mn);
        s = s * sc + w;
        acc.x = acc.x * sc + w * vx;
        acc.y = acc.y * sc + w * vy;
        m = mn;
    }
    float inv = (s > 0.f) ? 1.f / s : 0.f;
    float2 o = {acc.x * inv, acc.y * inv};

    // beta gate: channels c0 = head*128 + 2*lane, c1 = c0+1
    int c0 = head * CH + lane * 2;
    float2 sk = ((const float2*)(skip + (size_t)n * HCW + head * CH))[lane];
    float part = o.x * Wb[c0] + o.y * Wb[c0 + 1]
               + sk.x * Wb[512 + c0] + sk.y * Wb[512 + c0 + 1]
               + (o.x - sk.x) * Wb[1024 + c0] + (o.y - sk.y) * Wb[1024 + c0 + 1];
    __shared__ float red[4];
#pragma unroll
    for (int off = 32; off; off >>= 1) part += __shfl_xor(part, off, 64);
    if (lane == 0) red[head] = part;
    __syncthreads();
    float tot = red[0] + red[1] + red[2] + red[3];
    float beta = 1.f / (1.f + __expf(-tot));
    float gx = beta * sk.x + (1.f - beta) * o.x;
    float gy = beta * sk.y + (1.f - beta) * o.y;
    ((float2*)(gated + (size_t)n * HCW + head * CH))[lane] = make_float2(gx, gy);

    // LN partial sums -> bucketed atomics (one 64B line per bucket)
    float ls = gx + gy, lq = gx * gx + gy * gy;
#pragma unroll
    for (int off = 32; off; off >>= 1) {
        ls += __shfl_xor(ls, off, 64);
        lq += __shfl_xor(lq, off, 64);
    }
    __shared__ float r2[8];
    if (lane == 0) { r2[head] = ls; r2[4 + head] = lq; }
    __syncthreads();
    if (threadIdx.x == 0) {
        int b = n & (NBUCK - 1);
        atomicAdd(&stats[b * 16], r2[0] + r2[1] + r2[2] + r2[3]);
        atomicAdd(&stats[b * 16 + 1], r2[4] + r2[5] + r2[6] + r2[7]);
    }
}

// ---------------- LN + proj MFMA + residual + relu ----------------
__global__ __launch_bounds__(256) void k_proj_mfma(
    const float* __restrict__ gated,           // [NN][512]
    const unsigned short* __restrict__ Wpt,    // [128][512] layer slice
    const float* __restrict__ bp,
    const float* __restrict__ lw, const float* __restrict__ lb,
    const float* __restrict__ stats,
    float* __restrict__ h, unsigned short* __restrict__ h_bf) {
    __shared__ unsigned short As[128 * 128];
    __shared__ unsigned short Bs[128 * 128];
    int row0 = blockIdx.x * 128;
    int t = threadIdx.x;
    float ssum = 0.f, sq = 0.f;
#pragma unroll 16
    for (int i = 0; i < NBUCK; i++) { ssum += stats[i * 16]; sq += stats[i * 16 + 1]; }
    const float invM = 1.f / (NN * 512.f);
    float mean = ssum * invM;
    float ms = sq * invM - mean * mean;
    float rstd = 1.f / (sqrtf(fmaxf(ms, 0.f)) + LN_EPS);
    int wave = t >> 6, lane = t & 63;
    int wr = (wave >> 1) * 64, wc = (wave & 1) * 64;
    int lr = lane & 15, lk = lane >> 4;
    f32x4 acc[4][4] = {};
    for (int kc = 0; kc < 4; kc++) {
        __syncthreads();
#pragma unroll
        for (int i = 0; i < 8; i++) {
            int c = t + i * 256;
            int r = c >> 4, cc = c & 15;
            int gr = row0 + r;
            int gk = kc * 128 + cc * 8;
            unsigned short u[8];
            if (gr < NN) {
                const float* g = gated + (size_t)gr * 512 + gk;
#pragma unroll
                for (int j = 0; j < 8; j++) {
                    float v = (g[j] - mean) * rstd * lw[gk + j] + lb[gk + j];
                    u[j] = f2bf(v);
                }
            } else {
#pragma unroll
                for (int j = 0; j < 8; j++) u[j] = 0;
            }
            int sc = (r << 4) | (cc ^ (r & 7));
            *(uint4*)(As + sc * 8) = *(uint4*)u;
        }
#pragma unroll
        for (int i = 0; i < 8; i++) {
            int c = t + i * 256;
            int r = c >> 4, cc = c & 15;
            uint4 v = *(const uint4*)(Wpt + (size_t)r * 512 + kc * 128 + cc * 8);
            int sc = (r << 4) | (cc ^ (r & 7));
            *(uint4*)(Bs + sc * 8) = v;
        }
        __syncthreads();
#pragma unroll
        for (int ks = 0; ks < 4; ks++) {
            bf16x8 a[4], b[4];
#pragma unroll
            for (int mi = 0; mi < 4; mi++) {
                int r = wr + mi * 16 + lr;
                int cc = (ks * 4 + lk) ^ (r & 7);
                a[mi] = *(const bf16x8*)(As + (((r << 4) | cc) * 8));
            }
#pragma unroll
            for (int ni = 0; ni < 4; ni++) {
                int r = wc + ni * 16 + lr;
                int cc = (ks * 4 + lk) ^ (r & 7);
                b[ni] = *(const bf16x8*)(Bs + (((r << 4) | cc) * 8));
            }
#pragma unroll
            for (int mi = 0; mi < 4; mi++)
#pragma unroll
                for (int ni = 0; ni < 4; ni++)
                    acc[mi][ni] = __builtin_amdgcn_mfma_f32_16x16x32_bf16(a[mi], b[ni], acc[mi][ni], 0, 0, 0);
        }
    }
#pragma unroll
    for (int ni = 0; ni < 4; ni++) {
        int gc = wc + ni * 16 + lr;  // 0..127
        float bias = bp[gc];
#pragma unroll
        for (int mi = 0; mi < 4; mi++) {
            int gr0 = row0 + wr + mi * 16 + 4 * lk;
#pragma unroll
            for (int r = 0; r < 4; r++) {
                int grr = gr0 + r;
                if (grr < NN) {
                    float o = acc[mi][ni][r] + bias + h[(size_t)grr * 128 + gc];
                    o = fmaxf(o, 0.f);
                    h[(size_t)grr * 128 + gc] = o;
                    h_bf[(size_t)grr * 128 + gc] = f2bf(o);
                }
            }
        }
    }
}

// ---------------- output projection ----------------
__global__ void k_out(const float* __restrict__ h, const float* __restrict__ W,
                      const float* __restrict__ b, float* __restrict__ out) {
    int i = blockIdx.x * blockDim.x + threadIdx.x;
    if (i >= NN * 5) return;
    int n = i / 5, j = i % 5;
    float acc = b[j];
    for (int k = 0; k < 128; k++) acc += h[(size_t)n * 128 + k] * W[k * 5 + j];
    out[i] = acc;
}

extern "C" void kernel_launch(void* const* d_in, const int* in_sizes, int n_in,
                              void* d_out, int out_size, void* d_ws, size_t ws_size,
                              hipStream_t stream) {
    const float* x     = (const float*)d_in[0];
    const int* ei      = (const int*)d_in[1];
    const float* W_in  = (const float*)d_in[2];
    const float* b_in  = (const float*)d_in[3];
    const float* W_out = (const float*)d_in[4];
    const float* b_out = (const float*)d_in[5];
    const float* Wq    = (const float*)d_in[6];
    const float* bq    = (const float*)d_in[7];
    const float* Wk    = (const float*)d_in[8];
    const float* bk    = (const float*)d_in[9];
    const float* Wv    = (const float*)d_in[10];
    const float* bv    = (const float*)d_in[11];
    const float* Wsk   = (const float*)d_in[12];
    const float* bsk   = (const float*)d_in[13];
    const float* Wbeta = (const float*)d_in[14];
    const float* ln_w  = (const float*)d_in[15];
    const float* ln_b  = (const float*)d_in[16];
    const float* Wproj = (const float*)d_in[17];
    const float* bproj = (const float*)d_in[18];
    float* out = (float*)d_out;

    // workspace layout
    float* h     = (float*)d_ws;                    // N*128
    float* qb    = h + (size_t)NN * 128;            // N*512
    float* sb    = qb + (size_t)NN * 512;           // N*512
    float* stats = sb + (size_t)NN * 512;           // L*NBUCK*16
    int* offs = (int*)(stats + NLAYERS * NBUCK * 16);  // N+1
    int* cnt  = offs + (NN + 1);
    int* fill = cnt + NN;
    int* col  = fill + NN;                          // E
    unsigned short* h_bf = (unsigned short*)(((uintptr_t)(col + NE) + 15) & ~(uintptr_t)15);
    unsigned short* kb16 = h_bf + (size_t)NN * 128;
    unsigned short* vb16 = kb16 + (size_t)NN * 512;
    unsigned short* wt_qkvs = vb16 + (size_t)NN * 512;             // L*2048*128
    unsigned short* wpt = wt_qkvs + (size_t)NLAYERS * 2048 * 128;  // L*128*512
    float* gated = qb;  // alias (block n reads q row n before writing row n)

    const int* src = ei;
    const int* dst = ei + NE;

    k_init<<<(NN + 255) / 256, 256, 0, stream>>>(cnt, fill, stats);
    k_count<<<(NE + 255) / 256, 256, 0, stream>>>(dst, cnt);
    k_scan<<<1, 1024, 0, stream>>>(cnt, offs);
    k_fill<<<(NE + 255) / 256, 256, 0, stream>>>(src, dst, offs, fill, col);
    {
        int tot = NLAYERS * 2048 * 128 + NLAYERS * 128 * 512;
        k_wconv<<<(tot + 255) / 256, 256, 0, stream>>>(Wq, Wk, Wv, Wsk, Wproj, wt_qkvs, wpt);
    }
    k_inproj<<<NN, 128, 0, stream>>>(x, W_in, b_in, h, h_bf);

    for (int l = 0; l < NLAYERS; ++l) {
        const unsigned short* Wt_ = wt_qkvs + (size_t)l * 2048 * 128;
        const unsigned short* Wp_ = wpt + (size_t)l * 128 * 512;
        const float* bq_ = bq + l * 512;
        const float* bk_ = bk + l * 512;
        const float* bv_ = bv + l * 512;
        const float* bs_ = bsk + l * 512;
        const float* Wb_ = Wbeta + (size_t)l * 1536;
        const float* lw_ = ln_w + l * 512;
        const float* lb_ = ln_b + l * 512;
        const float* bp_ = bproj + l * 128;
        float* st = stats + (size_t)l * NBUCK * 16;

        dim3 g1((NN + 127) / 128, 16);
        k_qkvs_mfma<<<g1, 256, 0, stream>>>(h_bf, Wt_, bq_, bk_, bv_, bs_,
                                            qb, kb16, vb16, sb);
        k_attn_beta<<<NN, 256, 0, stream>>>(qb, kb16, vb16, sb, Wb_, offs, col, gated, st);
        k_proj_mfma<<<(NN + 127) / 128, 256, 0, stream>>>(gated, Wp_, bp_, lw_, lb_, st, h, h_bf);
    }
    k_out<<<(NN * 5 + 255) / 256, 256, 0, stream>>>(h, W_out, b_out, out);
}

// Round 4
// 667.423 us; speedup vs baseline: 4.0696x; 1.0729x over previous
//
#include <hip/hip_runtime.h>
#include <math.h>

#define NN 10000
#define NE 160000
#define HCW 512
#define CH 128
#define NLAYERS 4
#define LN_EPS 1e-5f
#define NBUCK 128   // LN-stat atomic buckets, each on its own 64B line

typedef short bf16x8 __attribute__((ext_vector_type(8)));
typedef float f32x4 __attribute__((ext_vector_type(4)));

__device__ inline unsigned short f2bf(float f) {
    union { float f; unsigned int u; } x; x.f = f;
    unsigned int u = x.u;
    return (unsigned short)((u + 0x7FFFu + ((u >> 16) & 1u)) >> 16);
}
__device__ inline float bf2f(unsigned short s) {
    union { unsigned int u; float f; } x; x.u = ((unsigned int)s) << 16;
    return x.f;
}

// ---------------- CSR build ----------------
__global__ void k_init(int* cnt, int* fill, float* stats) {
    int i = blockIdx.x * blockDim.x + threadIdx.x;
    if (i < NN) { cnt[i] = 0; fill[i] = 0; }
    if (i < NLAYERS * NBUCK * 16) stats[i] = 0.f;
}

__global__ void k_count(const int* __restrict__ dst, int* __restrict__ cnt) {
    int e = blockIdx.x * blockDim.x + threadIdx.x;
    if (e < NE) atomicAdd(&cnt[dst[e]], 1);
}

__global__ __launch_bounds__(1024) void k_scan(const int* __restrict__ cnt, int* __restrict__ offs) {
    __shared__ int sh[1024];
    __shared__ int carry;
    if (threadIdx.x == 0) carry = 0;
    __syncthreads();
    for (int base = 0; base < NN; base += 1024) {
        int i = base + threadIdx.x;
        int v = (i < NN) ? cnt[i] : 0;
        sh[threadIdx.x] = v;
        __syncthreads();
        for (int off = 1; off < 1024; off <<= 1) {
            int t = (threadIdx.x >= off) ? sh[threadIdx.x - off] : 0;
            __syncthreads();
            sh[threadIdx.x] += t;
            __syncthreads();
        }
        int incl = sh[threadIdx.x];
        if (i < NN) offs[i] = carry + incl - v;
        __syncthreads();
        if (threadIdx.x == 1023) carry += sh[1023];
        __syncthreads();
    }
    if (threadIdx.x == 0) offs[NN] = carry;
}

__global__ void k_fill(const int* __restrict__ src, const int* __restrict__ dst,
                       const int* __restrict__ offs, int* __restrict__ fill,
                       int* __restrict__ col) {
    int e = blockIdx.x * blockDim.x + threadIdx.x;
    if (e < NE) {
        int d = dst[e];
        int p = offs[d] + atomicAdd(&fill[d], 1);
        col[p] = src[e];
    }
}

// ---------------- weight convert: fp32 -> bf16, [K][N] -> [N][K] ----------------
__global__ void k_wconv(const float* __restrict__ Wq, const float* __restrict__ Wk,
                        const float* __restrict__ Wv, const float* __restrict__ Ws,
                        const float* __restrict__ Wp,
                        unsigned short* __restrict__ wt_qkvs,   // [L][2048][128]
                        unsigned short* __restrict__ wpt) {     // [L][128][512]
    int id = blockIdx.x * blockDim.x + threadIdx.x;
    if (id < NLAYERS * 2048 * 128) {
        int l = id >> 18;
        int rem = id & 262143;
        int n = rem >> 7, k = rem & 127;
        int mat = n >> 9, wcol = n & 511;
        const float* W = (mat == 0) ? Wq : (mat == 1) ? Wk : (mat == 2) ? Wv : Ws;
        wt_qkvs[id] = f2bf(W[(size_t)l * 65536 + k * 512 + wcol]);
    } else if (id < NLAYERS * 2048 * 128 + NLAYERS * 128 * 512) {
        int id2 = id - NLAYERS * 2048 * 128;
        int l = id2 >> 16;
        int rem = id2 & 65535;
        int n = rem >> 9, k = rem & 511;
        wpt[(size_t)l * 65536 + n * 512 + k] = f2bf(Wp[(size_t)l * 65536 + k * 128 + n]);
    }
}

// ---------------- input projection ----------------
__global__ __launch_bounds__(128) void k_inproj(const float* __restrict__ x,
                                                const float* __restrict__ W,
                                                const float* __restrict__ b,
                                                float* __restrict__ h,
                                                unsigned short* __restrict__ h_bf) {
    int n = blockIdx.x;
    int j = threadIdx.x;
    float acc = b[j];
#pragma unroll
    for (int i = 0; i < 15; i++) acc += x[n * 15 + i] * W[i * 128 + j];
    h[n * 128 + j] = acc;
    h_bf[n * 128 + j] = f2bf(acc);
}

// ---------------- fused qkv+skip MFMA GEMM ----------------
__global__ __launch_bounds__(256) void k_qkvs_mfma(
    const unsigned short* __restrict__ h_bf,   // [NN][128]
    const unsigned short* __restrict__ Wt,     // [2048][128] layer slice
    const float* __restrict__ bq, const float* __restrict__ bk,
    const float* __restrict__ bv, const float* __restrict__ bs,
    float* __restrict__ qb, unsigned short* __restrict__ kb16,
    unsigned short* __restrict__ vb16, float* __restrict__ sb) {
    __shared__ unsigned short As[128 * 128];
    __shared__ unsigned short Bs[128 * 128];
    int row0 = blockIdx.x * 128;
    int n0 = blockIdx.y * 128;
    int t = threadIdx.x;
#pragma unroll
    for (int i = 0; i < 8; i++) {
        int c = t + i * 256;
        int r = c >> 4, cc = c & 15;
        int gr = row0 + r;
        uint4 v = make_uint4(0, 0, 0, 0);
        if (gr < NN) v = *(const uint4*)(h_bf + (size_t)gr * 128 + cc * 8);
        int sc = (r << 4) | (cc ^ (r & 7));
        *(uint4*)(As + sc * 8) = v;
    }
#pragma unroll
    for (int i = 0; i < 8; i++) {
        int c = t + i * 256;
        int r = c >> 4, cc = c & 15;
        uint4 v = *(const uint4*)(Wt + (size_t)(n0 + r) * 128 + cc * 8);
        int sc = (r << 4) | (cc ^ (r & 7));
        *(uint4*)(Bs + sc * 8) = v;
    }
    __syncthreads();
    int wave = t >> 6, lane = t & 63;
    int wr = (wave >> 1) * 64, wc = (wave & 1) * 64;
    int lr = lane & 15, lk = lane >> 4;
    f32x4 acc[4][4] = {};
#pragma unroll
    for (int ks = 0; ks < 4; ks++) {
        bf16x8 a[4], b[4];
#pragma unroll
        for (int mi = 0; mi < 4; mi++) {
            int r = wr + mi * 16 + lr;
            int cc = (ks * 4 + lk) ^ (r & 7);
            a[mi] = *(const bf16x8*)(As + (((r << 4) | cc) * 8));
        }
#pragma unroll
        for (int ni = 0; ni < 4; ni++) {
            int r = wc + ni * 16 + lr;
            int cc = (ks * 4 + lk) ^ (r & 7);
            b[ni] = *(const bf16x8*)(Bs + (((r << 4) | cc) * 8));
        }
#pragma unroll
        for (int mi = 0; mi < 4; mi++)
#pragma unroll
            for (int ni = 0; ni < 4; ni++)
                acc[mi][ni] = __builtin_amdgcn_mfma_f32_16x16x32_bf16(a[mi], b[ni], acc[mi][ni], 0, 0, 0);
    }
#pragma unroll
    for (int ni = 0; ni < 4; ni++) {
        int gc = n0 + wc + ni * 16 + lr;
        int mat = gc >> 9, wcol = gc & 511;
        float bias = ((mat == 0) ? bq : (mat == 1) ? bk : (mat == 2) ? bv : bs)[wcol];
#pragma unroll
        for (int mi = 0; mi < 4; mi++) {
            int gr0 = row0 + wr + mi * 16 + 4 * lk;
#pragma unroll
            for (int r = 0; r < 4; r++) {
                int grr = gr0 + r;
                if (grr < NN) {
                    float val = acc[mi][ni][r] + bias;
                    if (mat == 0)      qb[(size_t)grr * 512 + wcol] = val;
                    else if (mat == 3) sb[(size_t)grr * 512 + wcol] = val;
                    else if (mat == 1) kb16[(size_t)grr * 512 + wcol] = f2bf(val);
                    else               vb16[(size_t)grr * 512 + wcol] = f2bf(val);
                }
            }
        }
    }
}

// ---------------- fused attention + beta gate + LN stats ----------------
// one block per node, one wave per head; each wave: 2 half-waves x 2 ILP states
// = 4 edges in flight. gated aliases qb (block n reads q row n before write).
__global__ __launch_bounds__(256) void k_attn_beta(
    const float* __restrict__ qb,
    const unsigned short* __restrict__ kb16,
    const unsigned short* __restrict__ vb16,
    const float* __restrict__ skip,
    const float* __restrict__ Wb,
    const int* __restrict__ offs, const int* __restrict__ col,
    float* __restrict__ gated, float* __restrict__ stats) {
    int n = blockIdx.x;
    int head = threadIdx.x >> 6;
    int lane = threadIdx.x & 63;
    int half = lane >> 5;
    int sl = lane & 31;
    const size_t hbase = (size_t)head * CH;
    const float4 qv = *(const float4*)(qb + (size_t)n * HCW + hbase + sl * 4);
    int beg = offs[n], end = offs[n + 1];
    const float scale = 0.08838834764831845f;  // 1/sqrt(128)

    float mA = -INFINITY, sA = 0.f, mB = -INFINITY, sB = 0.f;
    float4 aA = {0.f, 0.f, 0.f, 0.f}, aB = {0.f, 0.f, 0.f, 0.f};

    for (int p = beg + half; p < end; p += 4) {
        int pB = p + 2;
        bool hasB = (pB < end);            // uniform within half
        int snA = col[p];
        int snB = hasB ? col[pB] : snA;
        uint2 kkA = *(const uint2*)(kb16 + (size_t)snA * HCW + hbase + sl * 4);
        uint2 vvA = *(const uint2*)(vb16 + (size_t)snA * HCW + hbase + sl * 4);
        uint2 kkB = *(const uint2*)(kb16 + (size_t)snB * HCW + hbase + sl * 4);
        uint2 vvB = *(const uint2*)(vb16 + (size_t)snB * HCW + hbase + sl * 4);

        float pa = qv.x * bf2f((unsigned short)(kkA.x & 0xffff))
                 + qv.y * bf2f((unsigned short)(kkA.x >> 16))
                 + qv.z * bf2f((unsigned short)(kkA.y & 0xffff))
                 + qv.w * bf2f((unsigned short)(kkA.y >> 16));
        float pb = qv.x * bf2f((unsigned short)(kkB.x & 0xffff))
                 + qv.y * bf2f((unsigned short)(kkB.x >> 16))
                 + qv.z * bf2f((unsigned short)(kkB.y & 0xffff))
                 + qv.w * bf2f((unsigned short)(kkB.y >> 16));
#pragma unroll
        for (int off = 16; off; off >>= 1) {
            pa += __shfl_xor(pa, off, 64);   // stays within 32-lane half
            pb += __shfl_xor(pb, off, 64);
        }
        {   // state A update
            float logit = pa * scale;
            float mn = fmaxf(mA, logit);
            float sc = __expf(mA - mn);
            float w = __expf(logit - mn);
            sA = sA * sc + w;
            aA.x = aA.x * sc + w * bf2f((unsigned short)(vvA.x & 0xffff));
            aA.y = aA.y * sc + w * bf2f((unsigned short)(vvA.x >> 16));
            aA.z = aA.z * sc + w * bf2f((unsigned short)(vvA.y & 0xffff));
            aA.w = aA.w * sc + w * bf2f((unsigned short)(vvA.y >> 16));
            mA = mn;
        }
        if (hasB) {
            float logit = pb * scale;
            float mn = fmaxf(mB, logit);
            float sc = __expf(mB - mn);
            float w = __expf(logit - mn);
            sB = sB * sc + w;
            aB.x = aB.x * sc + w * bf2f((unsigned short)(vvB.x & 0xffff));
            aB.y = aB.y * sc + w * bf2f((unsigned short)(vvB.x >> 16));
            aB.z = aB.z * sc + w * bf2f((unsigned short)(vvB.y & 0xffff));
            aB.w = aB.w * sc + w * bf2f((unsigned short)(vvB.y >> 16));
            mB = mn;
        }
    }
    // merge B into A (per-lane, same channels)
    {
        float mn = fmaxf(mA, mB);
        float c1 = (sA > 0.f) ? __expf(mA - mn) : 0.f;
        float c2 = (sB > 0.f) ? __expf(mB - mn) : 0.f;
        sA = sA * c1 + sB * c2;
        aA.x = aA.x * c1 + aB.x * c2;
        aA.y = aA.y * c1 + aB.y * c2;
        aA.z = aA.z * c1 + aB.z * c2;
        aA.w = aA.w * c1 + aB.w * c2;
        mA = mn;
    }
    // merge across halves (lane ^ 32 holds same channels)
    float m_o = __shfl_xor(mA, 32, 64);
    float s_o = __shfl_xor(sA, 32, 64);
    float4 a_o;
    a_o.x = __shfl_xor(aA.x, 32, 64);
    a_o.y = __shfl_xor(aA.y, 32, 64);
    a_o.z = __shfl_xor(aA.z, 32, 64);
    a_o.w = __shfl_xor(aA.w, 32, 64);
    float mn = fmaxf(mA, m_o);
    float c1 = (sA > 0.f) ? __expf(mA - mn) : 0.f;
    float c2 = (s_o > 0.f) ? __expf(m_o - mn) : 0.f;
    float st = sA * c1 + s_o * c2;
    float inv = (st > 0.f) ? 1.f / st : 0.f;
    float4 o;
    o.x = (aA.x * c1 + a_o.x * c2) * inv;
    o.y = (aA.y * c1 + a_o.y * c2) * inv;
    o.z = (aA.z * c1 + a_o.z * c2) * inv;
    o.w = (aA.w * c1 + a_o.w * c2) * inv;

    __shared__ float att_s[512];
    if (half == 0) *(float4*)(att_s + hbase + sl * 4) = o;
    __syncthreads();

    // beta gate: channels c0 = head*128 + 2*lane, c1 = c0+1
    int c0 = head * CH + lane * 2;
    float o0 = att_s[c0], o1 = att_s[c0 + 1];
    float2 sk = ((const float2*)(skip + (size_t)n * HCW + hbase))[lane];
    float part = o0 * Wb[c0] + o1 * Wb[c0 + 1]
               + sk.x * Wb[512 + c0] + sk.y * Wb[512 + c0 + 1]
               + (o0 - sk.x) * Wb[1024 + c0] + (o1 - sk.y) * Wb[1024 + c0 + 1];
    __shared__ float red[4];
#pragma unroll
    for (int off = 32; off; off >>= 1) part += __shfl_xor(part, off, 64);
    if (lane == 0) red[head] = part;
    __syncthreads();
    float tot = red[0] + red[1] + red[2] + red[3];
    float beta = 1.f / (1.f + __expf(-tot));
    float gx = beta * sk.x + (1.f - beta) * o0;
    float gy = beta * sk.y + (1.f - beta) * o1;
    ((float2*)(gated + (size_t)n * HCW + hbase))[lane] = make_float2(gx, gy);

    // LN partial sums -> bucketed atomics
    float ls = gx + gy, lq = gx * gx + gy * gy;
#pragma unroll
    for (int off = 32; off; off >>= 1) {
        ls += __shfl_xor(ls, off, 64);
        lq += __shfl_xor(lq, off, 64);
    }
    __shared__ float r2[8];
    if (lane == 0) { r2[head] = ls; r2[4 + head] = lq; }
    __syncthreads();
    if (threadIdx.x == 0) {
        int b = n & (NBUCK - 1);
        atomicAdd(&stats[b * 16], r2[0] + r2[1] + r2[2] + r2[3]);
        atomicAdd(&stats[b * 16 + 1], r2[4] + r2[5] + r2[6] + r2[7]);
    }
}

// ---------------- LN + proj MFMA + residual + relu ----------------
__global__ __launch_bounds__(256) void k_proj_mfma(
    const float* __restrict__ gated,           // [NN][512]
    const unsigned short* __restrict__ Wpt,    // [128][512] layer slice
    const float* __restrict__ bp,
    const float* __restrict__ lw, const float* __restrict__ lb,
    const float* __restrict__ stats,
    float* __restrict__ h, unsigned short* __restrict__ h_bf) {
    __shared__ unsigned short As[128 * 128];
    __shared__ unsigned short Bs[128 * 128];
    int row0 = blockIdx.x * 128;
    int t = threadIdx.x;
    float ssum = 0.f, sq = 0.f;
#pragma unroll 16
    for (int i = 0; i < NBUCK; i++) { ssum += stats[i * 16]; sq += stats[i * 16 + 1]; }
    const float invM = 1.f / (NN * 512.f);
    float mean = ssum * invM;
    float ms = sq * invM - mean * mean;
    float rstd = 1.f / (sqrtf(fmaxf(ms, 0.f)) + LN_EPS);
    int wave = t >> 6, lane = t & 63;
    int wr = (wave >> 1) * 64, wc = (wave & 1) * 64;
    int lr = lane & 15, lk = lane >> 4;
    f32x4 acc[4][4] = {};
    for (int kc = 0; kc < 4; kc++) {
        __syncthreads();
#pragma unroll
        for (int i = 0; i < 8; i++) {
            int c = t + i * 256;
            int r = c >> 4, cc = c & 15;
            int gr = row0 + r;
            int gk = kc * 128 + cc * 8;
            unsigned short u[8];
            if (gr < NN) {
                const float* g = gated + (size_t)gr * 512 + gk;
#pragma unroll
                for (int j = 0; j < 8; j++) {
                    float v = (g[j] - mean) * rstd * lw[gk + j] + lb[gk + j];
                    u[j] = f2bf(v);
                }
            } else {
#pragma unroll
                for (int j = 0; j < 8; j++) u[j] = 0;
            }
            int sc = (r << 4) | (cc ^ (r & 7));
            *(uint4*)(As + sc * 8) = *(uint4*)u;
        }
#pragma unroll
        for (int i = 0; i < 8; i++) {
            int c = t + i * 256;
            int r = c >> 4, cc = c & 15;
            uint4 v = *(const uint4*)(Wpt + (size_t)r * 512 + kc * 128 + cc * 8);
            int sc = (r << 4) | (cc ^ (r & 7));
            *(uint4*)(Bs + sc * 8) = v;
        }
        __syncthreads();
#pragma unroll
        for (int ks = 0; ks < 4; ks++) {
            bf16x8 a[4], b[4];
#pragma unroll
            for (int mi = 0; mi < 4; mi++) {
                int r = wr + mi * 16 + lr;
                int cc = (ks * 4 + lk) ^ (r & 7);
                a[mi] = *(const bf16x8*)(As + (((r << 4) | cc) * 8));
            }
#pragma unroll
            for (int ni = 0; ni < 4; ni++) {
                int r = wc + ni * 16 + lr;
                int cc = (ks * 4 + lk) ^ (r & 7);
                b[ni] = *(const bf16x8*)(Bs + (((r << 4) | cc) * 8));
            }
#pragma unroll
            for (int mi = 0; mi < 4; mi++)
#pragma unroll
                for (int ni = 0; ni < 4; ni++)
                    acc[mi][ni] = __builtin_amdgcn_mfma_f32_16x16x32_bf16(a[mi], b[ni], acc[mi][ni], 0, 0, 0);
        }
    }
#pragma unroll
    for (int ni = 0; ni < 4; ni++) {
        int gc = wc + ni * 16 + lr;  // 0..127
        float bias = bp[gc];
#pragma unroll
        for (int mi = 0; mi < 4; mi++) {
            int gr0 = row0 + wr + mi * 16 + 4 * lk;
#pragma unroll
            for (int r = 0; r < 4; r++) {
                int grr = gr0 + r;
                if (grr < NN) {
                    float o = acc[mi][ni][r] + bias + h[(size_t)grr * 128 + gc];
                    o = fmaxf(o, 0.f);
                    h[(size_t)grr * 128 + gc] = o;
                    h_bf[(size_t)grr * 128 + gc] = f2bf(o);
                }
            }
        }
    }
}

// ---------------- output projection ----------------
__global__ void k_out(const float* __restrict__ h, const float* __restrict__ W,
                      const float* __restrict__ b, float* __restrict__ out) {
    int i = blockIdx.x * blockDim.x + threadIdx.x;
    if (i >= NN * 5) return;
    int n = i / 5, j = i % 5;
    float acc = b[j];
    for (int k = 0; k < 128; k++) acc += h[(size_t)n * 128 + k] * W[k * 5 + j];
    out[i] = acc;
}

extern "C" void kernel_launch(void* const* d_in, const int* in_sizes, int n_in,
                              void* d_out, int out_size, void* d_ws, size_t ws_size,
                              hipStream_t stream) {
    const float* x     = (const float*)d_in[0];
    const int* ei      = (const int*)d_in[1];
    const float* W_in  = (const float*)d_in[2];
    const float* b_in  = (const float*)d_in[3];
    const float* W_out = (const float*)d_in[4];
    const float* b_out = (const float*)d_in[5];
    const float* Wq    = (const float*)d_in[6];
    const float* bq    = (const float*)d_in[7];
    const float* Wk    = (const float*)d_in[8];
    const float* bk    = (const float*)d_in[9];
    const float* Wv    = (const float*)d_in[10];
    const float* bv    = (const float*)d_in[11];
    const float* Wsk   = (const float*)d_in[12];
    const float* bsk   = (const float*)d_in[13];
    const float* Wbeta = (const float*)d_in[14];
    const float* ln_w  = (const float*)d_in[15];
    const float* ln_b  = (const float*)d_in[16];
    const float* Wproj = (const float*)d_in[17];
    const float* bproj = (const float*)d_in[18];
    float* out = (float*)d_out;

    // workspace layout
    float* h     = (float*)d_ws;                    // N*128
    float* qb    = h + (size_t)NN * 128;            // N*512
    float* sb    = qb + (size_t)NN * 512;           // N*512
    float* stats = sb + (size_t)NN * 512;           // L*NBUCK*16
    int* offs = (int*)(stats + NLAYERS * NBUCK * 16);  // N+1
    int* cnt  = offs + (NN + 1);
    int* fill = cnt + NN;
    int* col  = fill + NN;                          // E
    unsigned short* h_bf = (unsigned short*)(((uintptr_t)(col + NE) + 15) & ~(uintptr_t)15);
    unsigned short* kb16 = h_bf + (size_t)NN * 128;
    unsigned short* vb16 = kb16 + (size_t)NN * 512;
    unsigned short* wt_qkvs = vb16 + (size_t)NN * 512;             // L*2048*128
    unsigned short* wpt = wt_qkvs + (size_t)NLAYERS * 2048 * 128;  // L*128*512
    float* gated = qb;  // alias (block n reads q row n before writing row n)

    const int* src = ei;
    const int* dst = ei + NE;

    k_init<<<(NN + 255) / 256, 256, 0, stream>>>(cnt, fill, stats);
    k_count<<<(NE + 255) / 256, 256, 0, stream>>>(dst, cnt);
    k_scan<<<1, 1024, 0, stream>>>(cnt, offs);
    k_fill<<<(NE + 255) / 256, 256, 0, stream>>>(src, dst, offs, fill, col);
    {
        int tot = NLAYERS * 2048 * 128 + NLAYERS * 128 * 512;
        k_wconv<<<(tot + 255) / 256, 256, 0, stream>>>(Wq, Wk, Wv, Wsk, Wproj, wt_qkvs, wpt);
    }
    k_inproj<<<NN, 128, 0, stream>>>(x, W_in, b_in, h, h_bf);

    for (int l = 0; l < NLAYERS; ++l) {
        const unsigned short* Wt_ = wt_qkvs + (size_t)l * 2048 * 128;
        const unsigned short* Wp_ = wpt + (size_t)l * 128 * 512;
        const float* bq_ = bq + l * 512;
        const float* bk_ = bk + l * 512;
        const float* bv_ = bv + l * 512;
        const float* bs_ = bsk + l * 512;
        const float* Wb_ = Wbeta + (size_t)l * 1536;
        const float* lw_ = ln_w + l * 512;
        const float* lb_ = ln_b + l * 512;
        const float* bp_ = bproj + l * 128;
        float* st = stats + (size_t)l * NBUCK * 16;

        dim3 g1((NN + 127) / 128, 16);
        k_qkvs_mfma<<<g1, 256, 0, stream>>>(h_bf, Wt_, bq_, bk_, bv_, bs_,
                                            qb, kb16, vb16, sb);
        k_attn_beta<<<NN, 256, 0, stream>>>(qb, kb16, vb16, sb, Wb_, offs, col, gated, st);
        k_proj_mfma<<<(NN + 127) / 128, 256, 0, stream>>>(gated, Wp_, bp_, lw_, lb_, st, h, h_bf);
    }
    k_out<<<(NN * 5 + 255) / 256, 256, 0, stream>>>(h, W_out, b_out, out);
}

// Round 5
// 570.979 us; speedup vs baseline: 4.7570x; 1.1689x over previous
//
#include <hip/hip_runtime.h>
#include <math.h>

#define NN 10000
#define NE 160000
#define HCW 512
#define CH 128
#define NLAYERS 4
#define LN_EPS 1e-5f
#define NBUCK 128   // LN-stat atomic buckets, each on its own 64B line

typedef short bf16x8 __attribute__((ext_vector_type(8)));
typedef float f32x4 __attribute__((ext_vector_type(4)));

__device__ inline unsigned short f2bf(float f) {
    union { float f; unsigned int u; } x; x.f = f;
    unsigned int u = x.u;
    return (unsigned short)((u + 0x7FFFu + ((u >> 16) & 1u)) >> 16);
}
__device__ inline float bf2f(unsigned short s) {
    union { unsigned int u; float f; } x; x.u = ((unsigned int)s) << 16;
    return x.f;
}
__device__ inline float lo16(unsigned int u) {
    union { unsigned int x; float f; } v; v.x = u << 16; return v.f;
}
__device__ inline float hi16(unsigned int u) {
    union { unsigned int x; float f; } v; v.x = u & 0xffff0000u; return v.f;
}

// ---------------- CSR build ----------------
__global__ void k_init(int* cnt, int* fill, float* stats) {
    int i = blockIdx.x * blockDim.x + threadIdx.x;
    if (i < NN) { cnt[i] = 0; fill[i] = 0; }
    if (i < NLAYERS * NBUCK * 16) stats[i] = 0.f;
}

__global__ void k_count(const int* __restrict__ dst, int* __restrict__ cnt) {
    int e = blockIdx.x * blockDim.x + threadIdx.x;
    if (e < NE) atomicAdd(&cnt[dst[e]], 1);
}

__global__ __launch_bounds__(1024) void k_scan(const int* __restrict__ cnt, int* __restrict__ offs) {
    __shared__ int sh[1024];
    __shared__ int carry;
    if (threadIdx.x == 0) carry = 0;
    __syncthreads();
    for (int base = 0; base < NN; base += 1024) {
        int i = base + threadIdx.x;
        int v = (i < NN) ? cnt[i] : 0;
        sh[threadIdx.x] = v;
        __syncthreads();
        for (int off = 1; off < 1024; off <<= 1) {
            int t = (threadIdx.x >= off) ? sh[threadIdx.x - off] : 0;
            __syncthreads();
            sh[threadIdx.x] += t;
            __syncthreads();
        }
        int incl = sh[threadIdx.x];
        if (i < NN) offs[i] = carry + incl - v;
        __syncthreads();
        if (threadIdx.x == 1023) carry += sh[1023];
        __syncthreads();
    }
    if (threadIdx.x == 0) offs[NN] = carry;
}

__global__ void k_fill(const int* __restrict__ src, const int* __restrict__ dst,
                       const int* __restrict__ offs, int* __restrict__ fill,
                       int* __restrict__ col) {
    int e = blockIdx.x * blockDim.x + threadIdx.x;
    if (e < NE) {
        int d = dst[e];
        int p = offs[d] + atomicAdd(&fill[d], 1);
        col[p] = src[e];
    }
}

// ---------------- weight convert: fp32 -> bf16, [K][N] -> [N][K] ----------------
__global__ void k_wconv(const float* __restrict__ Wq, const float* __restrict__ Wk,
                        const float* __restrict__ Wv, const float* __restrict__ Ws,
                        const float* __restrict__ Wp,
                        unsigned short* __restrict__ wt_qkvs,   // [L][2048][128]
                        unsigned short* __restrict__ wpt) {     // [L][128][512]
    int id = blockIdx.x * blockDim.x + threadIdx.x;
    if (id < NLAYERS * 2048 * 128) {
        int l = id >> 18;
        int rem = id & 262143;
        int n = rem >> 7, k = rem & 127;
        int mat = n >> 9, wcol = n & 511;
        const float* W = (mat == 0) ? Wq : (mat == 1) ? Wk : (mat == 2) ? Wv : Ws;
        wt_qkvs[id] = f2bf(W[(size_t)l * 65536 + k * 512 + wcol]);
    } else if (id < NLAYERS * 2048 * 128 + NLAYERS * 128 * 512) {
        int id2 = id - NLAYERS * 2048 * 128;
        int l = id2 >> 16;
        int rem = id2 & 65535;
        int n = rem >> 9, k = rem & 511;
        wpt[(size_t)l * 65536 + n * 512 + k] = f2bf(Wp[(size_t)l * 65536 + k * 128 + n]);
    }
}

// ---------------- input projection ----------------
__global__ __launch_bounds__(128) void k_inproj(const float* __restrict__ x,
                                                const float* __restrict__ W,
                                                const float* __restrict__ b,
                                                float* __restrict__ h,
                                                unsigned short* __restrict__ h_bf) {
    int n = blockIdx.x;
    int j = threadIdx.x;
    float acc = b[j];
#pragma unroll
    for (int i = 0; i < 15; i++) acc += x[n * 15 + i] * W[i * 128 + j];
    h[n * 128 + j] = acc;
    h_bf[n * 128 + j] = f2bf(acc);
}

// ---------------- fused qkv+skip MFMA GEMM ----------------
__global__ __launch_bounds__(256) void k_qkvs_mfma(
    const unsigned short* __restrict__ h_bf,   // [NN][128]
    const unsigned short* __restrict__ Wt,     // [2048][128] layer slice
    const float* __restrict__ bq, const float* __restrict__ bk,
    const float* __restrict__ bv, const float* __restrict__ bs,
    float* __restrict__ qb, unsigned short* __restrict__ kb16,
    unsigned short* __restrict__ vb16, float* __restrict__ sb) {
    __shared__ unsigned short As[128 * 128];
    __shared__ unsigned short Bs[128 * 128];
    int row0 = blockIdx.x * 128;
    int n0 = blockIdx.y * 128;
    int t = threadIdx.x;
#pragma unroll
    for (int i = 0; i < 8; i++) {
        int c = t + i * 256;
        int r = c >> 4, cc = c & 15;
        int gr = row0 + r;
        uint4 v = make_uint4(0, 0, 0, 0);
        if (gr < NN) v = *(const uint4*)(h_bf + (size_t)gr * 128 + cc * 8);
        int sc = (r << 4) | (cc ^ (r & 7));
        *(uint4*)(As + sc * 8) = v;
    }
#pragma unroll
    for (int i = 0; i < 8; i++) {
        int c = t + i * 256;
        int r = c >> 4, cc = c & 15;
        uint4 v = *(const uint4*)(Wt + (size_t)(n0 + r) * 128 + cc * 8);
        int sc = (r << 4) | (cc ^ (r & 7));
        *(uint4*)(Bs + sc * 8) = v;
    }
    __syncthreads();
    int wave = t >> 6, lane = t & 63;
    int wr = (wave >> 1) * 64, wc = (wave & 1) * 64;
    int lr = lane & 15, lk = lane >> 4;
    f32x4 acc[4][4] = {};
#pragma unroll
    for (int ks = 0; ks < 4; ks++) {
        bf16x8 a[4], b[4];
#pragma unroll
        for (int mi = 0; mi < 4; mi++) {
            int r = wr + mi * 16 + lr;
            int cc = (ks * 4 + lk) ^ (r & 7);
            a[mi] = *(const bf16x8*)(As + (((r << 4) | cc) * 8));
        }
#pragma unroll
        for (int ni = 0; ni < 4; ni++) {
            int r = wc + ni * 16 + lr;
            int cc = (ks * 4 + lk) ^ (r & 7);
            b[ni] = *(const bf16x8*)(Bs + (((r << 4) | cc) * 8));
        }
#pragma unroll
        for (int mi = 0; mi < 4; mi++)
#pragma unroll
            for (int ni = 0; ni < 4; ni++)
                acc[mi][ni] = __builtin_amdgcn_mfma_f32_16x16x32_bf16(a[mi], b[ni], acc[mi][ni], 0, 0, 0);
    }
#pragma unroll
    for (int ni = 0; ni < 4; ni++) {
        int gc = n0 + wc + ni * 16 + lr;
        int mat = gc >> 9, wcol = gc & 511;
        float bias = ((mat == 0) ? bq : (mat == 1) ? bk : (mat == 2) ? bv : bs)[wcol];
#pragma unroll
        for (int mi = 0; mi < 4; mi++) {
            int gr0 = row0 + wr + mi * 16 + 4 * lk;
#pragma unroll
            for (int r = 0; r < 4; r++) {
                int grr = gr0 + r;
                if (grr < NN) {
                    float val = acc[mi][ni][r] + bias;
                    if (mat == 0)      qb[(size_t)grr * 512 + wcol] = val;
                    else if (mat == 3) sb[(size_t)grr * 512 + wcol] = val;
                    else if (mat == 1) kb16[(size_t)grr * 512 + wcol] = f2bf(val);
                    else               vb16[(size_t)grr * 512 + wcol] = f2bf(val);
                }
            }
        }
    }
}

// ---------------- fused attention + beta gate + LN stats ----------------
// one block per node, one wave per head; 4 groups of 16 lanes, each group
// owns one edge at a time (8 channels/lane), defer-max online softmax.
__global__ __launch_bounds__(256) void k_attn_beta(
    const float* __restrict__ qb,
    const unsigned short* __restrict__ kb16,
    const unsigned short* __restrict__ vb16,
    const float* __restrict__ skip,
    const float* __restrict__ Wb,
    const int* __restrict__ offs, const int* __restrict__ col,
    float* __restrict__ gated, float* __restrict__ stats) {
    int n = blockIdx.x;
    int head = threadIdx.x >> 6;
    int lane = threadIdx.x & 63;
    int g = lane >> 4;         // edge group 0..3
    int subl = lane & 15;      // 8 channels per lane
    const int hbase = head * CH;
    const float* qrow = qb + (size_t)n * HCW + hbase + subl * 8;
    const float4 q0 = *(const float4*)qrow;
    const float4 q1 = *(const float4*)(qrow + 4);
    int beg = offs[n], end = offs[n + 1];
    const float scale = 0.08838834764831845f;  // 1/sqrt(128)

    float m = -INFINITY, s = 0.f;
    float4 a0 = {0.f, 0.f, 0.f, 0.f}, a1 = {0.f, 0.f, 0.f, 0.f};

    for (int p = beg + g; p < end; p += 4) {
        int sn = col[p];
        const unsigned short* kvb = kb16 + ((size_t)sn << 9) + hbase + subl * 8;
        uint4 kk = *(const uint4*)kvb;
        uint4 vv = *(const uint4*)(vb16 + ((size_t)sn << 9) + hbase + subl * 8);
        float d = q0.x * lo16(kk.x) + q0.y * hi16(kk.x)
                + q0.z * lo16(kk.y) + q0.w * hi16(kk.y)
                + q1.x * lo16(kk.z) + q1.y * hi16(kk.z)
                + q1.z * lo16(kk.w) + q1.w * hi16(kk.w);
#pragma unroll
        for (int off = 1; off < 16; off <<= 1) d += __shfl_xor(d, off, 64);
        float logit = d * scale;
        if (logit <= m + 8.f) {          // fast path: no rescale
            float w = __expf(logit - m);
            s += w;
            a0.x += w * lo16(vv.x); a0.y += w * hi16(vv.x);
            a0.z += w * lo16(vv.y); a0.w += w * hi16(vv.y);
            a1.x += w * lo16(vv.z); a1.y += w * hi16(vv.z);
            a1.z += w * lo16(vv.w); a1.w += w * hi16(vv.w);
        } else {                          // rescale (first edge & rare growth)
            float sc = __expf(m - logit); // m=-inf -> 0
            s = s * sc + 1.f;
            a0.x = a0.x * sc + lo16(vv.x); a0.y = a0.y * sc + hi16(vv.x);
            a0.z = a0.z * sc + lo16(vv.y); a0.w = a0.w * sc + hi16(vv.y);
            a1.x = a1.x * sc + lo16(vv.z); a1.y = a1.y * sc + hi16(vv.z);
            a1.z = a1.z * sc + lo16(vv.w); a1.w = a1.w * sc + hi16(vv.w);
            m = logit;
        }
    }
    // merge the 4 group states (lane^16, then lane^32 hold the same channels)
#pragma unroll
    for (int off = 16; off <= 32; off <<= 1) {
        float m_o = __shfl_xor(m, off, 64);
        float s_o = __shfl_xor(s, off, 64);
        float4 b0, b1;
        b0.x = __shfl_xor(a0.x, off, 64); b0.y = __shfl_xor(a0.y, off, 64);
        b0.z = __shfl_xor(a0.z, off, 64); b0.w = __shfl_xor(a0.w, off, 64);
        b1.x = __shfl_xor(a1.x, off, 64); b1.y = __shfl_xor(a1.y, off, 64);
        b1.z = __shfl_xor(a1.z, off, 64); b1.w = __shfl_xor(a1.w, off, 64);
        float mn = fmaxf(m, m_o);
        float c1 = (s > 0.f) ? __expf(m - mn) : 0.f;
        float c2 = (s_o > 0.f) ? __expf(m_o - mn) : 0.f;
        s = s * c1 + s_o * c2;
        a0.x = a0.x * c1 + b0.x * c2; a0.y = a0.y * c1 + b0.y * c2;
        a0.z = a0.z * c1 + b0.z * c2; a0.w = a0.w * c1 + b0.w * c2;
        a1.x = a1.x * c1 + b1.x * c2; a1.y = a1.y * c1 + b1.y * c2;
        a1.z = a1.z * c1 + b1.z * c2; a1.w = a1.w * c1 + b1.w * c2;
        m = mn;
    }
    float inv = (s > 0.f) ? 1.f / s : 0.f;

    __shared__ float att_s[512];
    if (g == 0) {
        float4 o0 = {a0.x * inv, a0.y * inv, a0.z * inv, a0.w * inv};
        float4 o1 = {a1.x * inv, a1.y * inv, a1.z * inv, a1.w * inv};
        *(float4*)(att_s + hbase + subl * 8) = o0;
        *(float4*)(att_s + hbase + subl * 8 + 4) = o1;
    }
    __syncthreads();

    // beta gate: channels c0 = head*128 + 2*lane, c1 = c0+1
    int c0 = hbase + lane * 2;
    float o0 = att_s[c0], o1 = att_s[c0 + 1];
    float2 sk = ((const float2*)(skip + (size_t)n * HCW + hbase))[lane];
    float part = o0 * Wb[c0] + o1 * Wb[c0 + 1]
               + sk.x * Wb[512 + c0] + sk.y * Wb[512 + c0 + 1]
               + (o0 - sk.x) * Wb[1024 + c0] + (o1 - sk.y) * Wb[1024 + c0 + 1];
    __shared__ float red[4];
#pragma unroll
    for (int off = 32; off; off >>= 1) part += __shfl_xor(part, off, 64);
    if (lane == 0) red[head] = part;
    __syncthreads();
    float tot = red[0] + red[1] + red[2] + red[3];
    float beta = 1.f / (1.f + __expf(-tot));
    float gx = beta * sk.x + (1.f - beta) * o0;
    float gy = beta * sk.y + (1.f - beta) * o1;
    ((float2*)(gated + (size_t)n * HCW + hbase))[lane] = make_float2(gx, gy);

    // LN partial sums -> bucketed atomics
    float ls = gx + gy, lq = gx * gx + gy * gy;
#pragma unroll
    for (int off = 32; off; off >>= 1) {
        ls += __shfl_xor(ls, off, 64);
        lq += __shfl_xor(lq, off, 64);
    }
    __shared__ float r2[8];
    if (lane == 0) { r2[head] = ls; r2[4 + head] = lq; }
    __syncthreads();
    if (threadIdx.x == 0) {
        int b = n & (NBUCK - 1);
        atomicAdd(&stats[b * 16], r2[0] + r2[1] + r2[2] + r2[3]);
        atomicAdd(&stats[b * 16 + 1], r2[4] + r2[5] + r2[6] + r2[7]);
    }
}

// ---------------- LN + proj MFMA + residual + relu ----------------
// 64-row tiles, 8 waves (512 thr): wave w computes 16 rows x 64 cols.
__global__ __launch_bounds__(512) void k_proj_mfma(
    const float* __restrict__ gated,           // [NN][512]
    const unsigned short* __restrict__ Wpt,    // [128][512] layer slice
    const float* __restrict__ bp,
    const float* __restrict__ lw, const float* __restrict__ lb,
    const float* __restrict__ stats,
    float* __restrict__ h, unsigned short* __restrict__ h_bf) {
    __shared__ unsigned short As[64 * 128];    // 16KB
    __shared__ unsigned short Bs[128 * 128];   // 32KB
    int row0 = blockIdx.x * 64;
    int t = threadIdx.x;
    float ssum = 0.f, sq = 0.f;
#pragma unroll 16
    for (int i = 0; i < NBUCK; i++) { ssum += stats[i * 16]; sq += stats[i * 16 + 1]; }
    const float invM = 1.f / (NN * 512.f);
    float mean = ssum * invM;
    float ms = sq * invM - mean * mean;
    float rstd = 1.f / (sqrtf(fmaxf(ms, 0.f)) + LN_EPS);
    int wave = t >> 6, lane = t & 63;
    int wr = (wave >> 1) * 16, wc = (wave & 1) * 64;
    int lr = lane & 15, lk = lane >> 4;
    f32x4 acc[4] = {};
    for (int kc = 0; kc < 4; kc++) {
        __syncthreads();
#pragma unroll
        for (int i = 0; i < 2; i++) {
            int c = t + i * 512;
            int r = c >> 4, cc = c & 15;
            int gr = row0 + r;
            int gk = kc * 128 + cc * 8;
            unsigned short u[8];
            if (gr < NN) {
                const float* gp = gated + (size_t)gr * 512 + gk;
#pragma unroll
                for (int j = 0; j < 8; j++) {
                    float v = (gp[j] - mean) * rstd * lw[gk + j] + lb[gk + j];
                    u[j] = f2bf(v);
                }
            } else {
#pragma unroll
                for (int j = 0; j < 8; j++) u[j] = 0;
            }
            int sc = (r << 4) | (cc ^ (r & 7));
            *(uint4*)(As + sc * 8) = *(uint4*)u;
        }
#pragma unroll
        for (int i = 0; i < 4; i++) {
            int c = t + i * 512;
            int r = c >> 4, cc = c & 15;
            uint4 v = *(const uint4*)(Wpt + (size_t)r * 512 + kc * 128 + cc * 8);
            int sc = (r << 4) | (cc ^ (r & 7));
            *(uint4*)(Bs + sc * 8) = v;
        }
        __syncthreads();
#pragma unroll
        for (int ks = 0; ks < 4; ks++) {
            bf16x8 a, b[4];
            {
                int r = wr + lr;
                int cc = (ks * 4 + lk) ^ (r & 7);
                a = *(const bf16x8*)(As + (((r << 4) | cc) * 8));
            }
#pragma unroll
            for (int ni = 0; ni < 4; ni++) {
                int r = wc + ni * 16 + lr;
                int cc = (ks * 4 + lk) ^ (r & 7);
                b[ni] = *(const bf16x8*)(Bs + (((r << 4) | cc) * 8));
            }
#pragma unroll
            for (int ni = 0; ni < 4; ni++)
                acc[ni] = __builtin_amdgcn_mfma_f32_16x16x32_bf16(a, b[ni], acc[ni], 0, 0, 0);
        }
    }
#pragma unroll
    for (int ni = 0; ni < 4; ni++) {
        int gc = wc + ni * 16 + lr;  // 0..127
        float bias = bp[gc];
        int gr0 = row0 + wr + 4 * lk;
#pragma unroll
        for (int r = 0; r < 4; r++) {
            int grr = gr0 + r;
            if (grr < NN) {
                float o = acc[ni][r] + bias + h[(size_t)grr * 128 + gc];
                o = fmaxf(o, 0.f);
                h[(size_t)grr * 128 + gc] = o;
                h_bf[(size_t)grr * 128 + gc] = f2bf(o);
            }
        }
    }
}

// ---------------- output projection ----------------
__global__ void k_out(const float* __restrict__ h, const float* __restrict__ W,
                      const float* __restrict__ b, float* __restrict__ out) {
    int i = blockIdx.x * blockDim.x + threadIdx.x;
    if (i >= NN * 5) return;
    int n = i / 5, j = i % 5;
    float acc = b[j];
    for (int k = 0; k < 128; k++) acc += h[(size_t)n * 128 + k] * W[k * 5 + j];
    out[i] = acc;
}

extern "C" void kernel_launch(void* const* d_in, const int* in_sizes, int n_in,
                              void* d_out, int out_size, void* d_ws, size_t ws_size,
                              hipStream_t stream) {
    const float* x     = (const float*)d_in[0];
    const int* ei      = (const int*)d_in[1];
    const float* W_in  = (const float*)d_in[2];
    const float* b_in  = (const float*)d_in[3];
    const float* W_out = (const float*)d_in[4];
    const float* b_out = (const float*)d_in[5];
    const float* Wq    = (const float*)d_in[6];
    const float* bq    = (const float*)d_in[7];
    const float* Wk    = (const float*)d_in[8];
    const float* bk    = (const float*)d_in[9];
    const float* Wv    = (const float*)d_in[10];
    const float* bv    = (const float*)d_in[11];
    const float* Wsk   = (const float*)d_in[12];
    const float* bsk   = (const float*)d_in[13];
    const float* Wbeta = (const float*)d_in[14];
    const float* ln_w  = (const float*)d_in[15];
    const float* ln_b  = (const float*)d_in[16];
    const float* Wproj = (const float*)d_in[17];
    const float* bproj = (const float*)d_in[18];
    float* out = (float*)d_out;

    // workspace layout
    float* h     = (float*)d_ws;                    // N*128
    float* qb    = h + (size_t)NN * 128;            // N*512
    float* sb    = qb + (size_t)NN * 512;           // N*512
    float* stats = sb + (size_t)NN * 512;           // L*NBUCK*16
    int* offs = (int*)(stats + NLAYERS * NBUCK * 16);  // N+1
    int* cnt  = offs + (NN + 1);
    int* fill = cnt + NN;
    int* col  = fill + NN;                          // E
    unsigned short* h_bf = (unsigned short*)(((uintptr_t)(col + NE) + 15) & ~(uintptr_t)15);
    unsigned short* kb16 = h_bf + (size_t)NN * 128;
    unsigned short* vb16 = kb16 + (size_t)NN * 512;
    unsigned short* wt_qkvs = vb16 + (size_t)NN * 512;             // L*2048*128
    unsigned short* wpt = wt_qkvs + (size_t)NLAYERS * 2048 * 128;  // L*128*512
    float* gated = qb;  // alias (block n reads q row n before writing row n)

    const int* src = ei;
    const int* dst = ei + NE;

    k_init<<<(NN + 255) / 256, 256, 0, stream>>>(cnt, fill, stats);
    k_count<<<(NE + 255) / 256, 256, 0, stream>>>(dst, cnt);
    k_scan<<<1, 1024, 0, stream>>>(cnt, offs);
    k_fill<<<(NE + 255) / 256, 256, 0, stream>>>(src, dst, offs, fill, col);
    {
        int tot = NLAYERS * 2048 * 128 + NLAYERS * 128 * 512;
        k_wconv<<<(tot + 255) / 256, 256, 0, stream>>>(Wq, Wk, Wv, Wsk, Wproj, wt_qkvs, wpt);
    }
    k_inproj<<<NN, 128, 0, stream>>>(x, W_in, b_in, h, h_bf);

    for (int l = 0; l < NLAYERS; ++l) {
        const unsigned short* Wt_ = wt_qkvs + (size_t)l * 2048 * 128;
        const unsigned short* Wp_ = wpt + (size_t)l * 128 * 512;
        const float* bq_ = bq + l * 512;
        const float* bk_ = bk + l * 512;
        const float* bv_ = bv + l * 512;
        const float* bs_ = bsk + l * 512;
        const float* Wb_ = Wbeta + (size_t)l * 1536;
        const float* lw_ = ln_w + l * 512;
        const float* lb_ = ln_b + l * 512;
        const float* bp_ = bproj + l * 128;
        float* st = stats + (size_t)l * NBUCK * 16;

        dim3 g1((NN + 127) / 128, 16);
        k_qkvs_mfma<<<g1, 256, 0, stream>>>(h_bf, Wt_, bq_, bk_, bv_, bs_,
                                            qb, kb16, vb16, sb);
        k_attn_beta<<<NN, 256, 0, stream>>>(qb, kb16, vb16, sb, Wb_, offs, col, gated, st);
        k_proj_mfma<<<(NN + 63) / 64, 512, 0, stream>>>(gated, Wp_, bp_, lw_, lb_, st, h, h_bf);
    }
    k_out<<<(NN * 5 + 255) / 256, 256, 0, stream>>>(h, W_out, b_out, out);
}

// Round 6
// 556.071 us; speedup vs baseline: 4.8845x; 1.0268x over previous
//
#include <hip/hip_runtime.h>
#include <math.h>

#define NN 10000
#define NE 160000
#define HCW 512
#define CH 128
#define NLAYERS 4
#define LN_EPS 1e-5f
#define NBUCK 128   // LN-stat atomic buckets, each on its own 64B line

typedef short bf16x8 __attribute__((ext_vector_type(8)));
typedef float f32x4 __attribute__((ext_vector_type(4)));

__device__ inline unsigned short f2bf(float f) {
    union { float f; unsigned int u; } x; x.f = f;
    unsigned int u = x.u;
    return (unsigned short)((u + 0x7FFFu + ((u >> 16) & 1u)) >> 16);
}
__device__ inline float bf2f(unsigned short s) {
    union { unsigned int u; float f; } x; x.u = ((unsigned int)s) << 16;
    return x.f;
}
__device__ inline float lo16(unsigned int u) {
    union { unsigned int x; float f; } v; v.x = u << 16; return v.f;
}
__device__ inline float hi16(unsigned int u) {
    union { unsigned int x; float f; } v; v.x = u & 0xffff0000u; return v.f;
}

// DPP row_ror add: dst lane i += src lane (i+N) mod 16 (within 16-lane row)
template<int CTRL>
__device__ inline float dppadd(float x) {
    int y = __builtin_amdgcn_update_dpp(0, __float_as_int(x), CTRL, 0xF, 0xF, true);
    return x + __int_as_float(y);
}
// full sum over each 16-lane row, result in all 16 lanes
__device__ inline float red16(float x) {
    x = dppadd<0x128>(x);  // row_ror:8
    x = dppadd<0x124>(x);  // row_ror:4
    x = dppadd<0x122>(x);  // row_ror:2
    x = dppadd<0x121>(x);  // row_ror:1
    return x;
}
__device__ inline float red64(float x) {
    x = red16(x);
    x += __shfl_xor(x, 16, 64);
    x += __shfl_xor(x, 32, 64);
    return x;
}

__device__ inline float dot8(const float4& q0, const float4& q1, const uint4& kk) {
    return q0.x * lo16(kk.x) + q0.y * hi16(kk.x)
         + q0.z * lo16(kk.y) + q0.w * hi16(kk.y)
         + q1.x * lo16(kk.z) + q1.y * hi16(kk.z)
         + q1.z * lo16(kk.w) + q1.w * hi16(kk.w);
}

// ---------------- CSR build ----------------
__global__ void k_init(int* cnt, int* fill, float* stats) {
    int i = blockIdx.x * blockDim.x + threadIdx.x;
    if (i < NN) { cnt[i] = 0; fill[i] = 0; }
    if (i < NLAYERS * NBUCK * 16) stats[i] = 0.f;
}

__global__ void k_count(const int* __restrict__ dst, int* __restrict__ cnt) {
    int e = blockIdx.x * blockDim.x + threadIdx.x;
    if (e < NE) atomicAdd(&cnt[dst[e]], 1);
}

__global__ __launch_bounds__(1024) void k_scan(const int* __restrict__ cnt, int* __restrict__ offs) {
    __shared__ int sh[1024];
    __shared__ int carry;
    if (threadIdx.x == 0) carry = 0;
    __syncthreads();
    for (int base = 0; base < NN; base += 1024) {
        int i = base + threadIdx.x;
        int v = (i < NN) ? cnt[i] : 0;
        sh[threadIdx.x] = v;
        __syncthreads();
        for (int off = 1; off < 1024; off <<= 1) {
            int t = (threadIdx.x >= off) ? sh[threadIdx.x - off] : 0;
            __syncthreads();
            sh[threadIdx.x] += t;
            __syncthreads();
        }
        int incl = sh[threadIdx.x];
        if (i < NN) offs[i] = carry + incl - v;
        __syncthreads();
        if (threadIdx.x == 1023) carry += sh[1023];
        __syncthreads();
    }
    if (threadIdx.x == 0) offs[NN] = carry;
}

__global__ void k_fill(const int* __restrict__ src, const int* __restrict__ dst,
                       const int* __restrict__ offs, int* __restrict__ fill,
                       int* __restrict__ col) {
    int e = blockIdx.x * blockDim.x + threadIdx.x;
    if (e < NE) {
        int d = dst[e];
        int p = offs[d] + atomicAdd(&fill[d], 1);
        col[p] = src[e];
    }
}

// ---------------- weight convert: fp32 -> bf16, [K][N] -> [N][K] ----------------
__global__ void k_wconv(const float* __restrict__ Wq, const float* __restrict__ Wk,
                        const float* __restrict__ Wv, const float* __restrict__ Ws,
                        const float* __restrict__ Wp,
                        unsigned short* __restrict__ wt_qkvs,   // [L][2048][128]
                        unsigned short* __restrict__ wpt) {     // [L][128][512]
    int id = blockIdx.x * blockDim.x + threadIdx.x;
    if (id < NLAYERS * 2048 * 128) {
        int l = id >> 18;
        int rem = id & 262143;
        int n = rem >> 7, k = rem & 127;
        int mat = n >> 9, wcol = n & 511;
        const float* W = (mat == 0) ? Wq : (mat == 1) ? Wk : (mat == 2) ? Wv : Ws;
        wt_qkvs[id] = f2bf(W[(size_t)l * 65536 + k * 512 + wcol]);
    } else if (id < NLAYERS * 2048 * 128 + NLAYERS * 128 * 512) {
        int id2 = id - NLAYERS * 2048 * 128;
        int l = id2 >> 16;
        int rem = id2 & 65535;
        int n = rem >> 9, k = rem & 511;
        wpt[(size_t)l * 65536 + n * 512 + k] = f2bf(Wp[(size_t)l * 65536 + k * 128 + n]);
    }
}

// ---------------- input projection ----------------
__global__ __launch_bounds__(128) void k_inproj(const float* __restrict__ x,
                                                const float* __restrict__ W,
                                                const float* __restrict__ b,
                                                float* __restrict__ h,
                                                unsigned short* __restrict__ h_bf) {
    int n = blockIdx.x;
    int j = threadIdx.x;
    float acc = b[j];
#pragma unroll
    for (int i = 0; i < 15; i++) acc += x[n * 15 + i] * W[i * 128 + j];
    h[n * 128 + j] = acc;
    h_bf[n * 128 + j] = f2bf(acc);
}

// ---------------- fused qkv+skip MFMA GEMM ----------------
// k,v outputs interleaved: kv16[node*1024 + 0..511]=K, +512..1023=V
__global__ __launch_bounds__(256) void k_qkvs_mfma(
    const unsigned short* __restrict__ h_bf,   // [NN][128]
    const unsigned short* __restrict__ Wt,     // [2048][128] layer slice
    const float* __restrict__ bq, const float* __restrict__ bk,
    const float* __restrict__ bv, const float* __restrict__ bs,
    float* __restrict__ qb, unsigned short* __restrict__ kv16,
    float* __restrict__ sb) {
    __shared__ unsigned short As[128 * 128];
    __shared__ unsigned short Bs[128 * 128];
    int row0 = blockIdx.x * 128;
    int n0 = blockIdx.y * 128;
    int t = threadIdx.x;
#pragma unroll
    for (int i = 0; i < 8; i++) {
        int c = t + i * 256;
        int r = c >> 4, cc = c & 15;
        int gr = row0 + r;
        uint4 v = make_uint4(0, 0, 0, 0);
        if (gr < NN) v = *(const uint4*)(h_bf + (size_t)gr * 128 + cc * 8);
        int sc = (r << 4) | (cc ^ (r & 7));
        *(uint4*)(As + sc * 8) = v;
    }
#pragma unroll
    for (int i = 0; i < 8; i++) {
        int c = t + i * 256;
        int r = c >> 4, cc = c & 15;
        uint4 v = *(const uint4*)(Wt + (size_t)(n0 + r) * 128 + cc * 8);
        int sc = (r << 4) | (cc ^ (r & 7));
        *(uint4*)(Bs + sc * 8) = v;
    }
    __syncthreads();
    int wave = t >> 6, lane = t & 63;
    int wr = (wave >> 1) * 64, wc = (wave & 1) * 64;
    int lr = lane & 15, lk = lane >> 4;
    f32x4 acc[4][4] = {};
#pragma unroll
    for (int ks = 0; ks < 4; ks++) {
        bf16x8 a[4], b[4];
#pragma unroll
        for (int mi = 0; mi < 4; mi++) {
            int r = wr + mi * 16 + lr;
            int cc = (ks * 4 + lk) ^ (r & 7);
            a[mi] = *(const bf16x8*)(As + (((r << 4) | cc) * 8));
        }
#pragma unroll
        for (int ni = 0; ni < 4; ni++) {
            int r = wc + ni * 16 + lr;
            int cc = (ks * 4 + lk) ^ (r & 7);
            b[ni] = *(const bf16x8*)(Bs + (((r << 4) | cc) * 8));
        }
#pragma unroll
        for (int mi = 0; mi < 4; mi++)
#pragma unroll
            for (int ni = 0; ni < 4; ni++)
                acc[mi][ni] = __builtin_amdgcn_mfma_f32_16x16x32_bf16(a[mi], b[ni], acc[mi][ni], 0, 0, 0);
    }
#pragma unroll
    for (int ni = 0; ni < 4; ni++) {
        int gc = n0 + wc + ni * 16 + lr;
        int mat = gc >> 9, wcol = gc & 511;
        float bias = ((mat == 0) ? bq : (mat == 1) ? bk : (mat == 2) ? bv : bs)[wcol];
#pragma unroll
        for (int mi = 0; mi < 4; mi++) {
            int gr0 = row0 + wr + mi * 16 + 4 * lk;
#pragma unroll
            for (int r = 0; r < 4; r++) {
                int grr = gr0 + r;
                if (grr < NN) {
                    float val = acc[mi][ni][r] + bias;
                    if (mat == 0)      qb[(size_t)grr * 512 + wcol] = val;
                    else if (mat == 3) sb[(size_t)grr * 512 + wcol] = val;
                    else if (mat == 1) kv16[((size_t)grr << 10) + wcol] = f2bf(val);
                    else               kv16[((size_t)grr << 10) + 512 + wcol] = f2bf(val);
                }
            }
        }
    }
}

// ---------------- fused attention + beta gate + LN stats ----------------
// one block per node, one wave per head; 4 groups of 16 lanes, each group
// runs 2 independent defer-max states (edges p, p+4) -> 8 edges in flight.
// DPP row_ror reduce for the 16-lane dots (no LDS pipe).
__global__ __launch_bounds__(256) void k_attn_beta(
    const float* __restrict__ qb,
    const unsigned short* __restrict__ kv16,
    const float* __restrict__ skip,
    const float* __restrict__ Wb,
    const int* __restrict__ offs, const int* __restrict__ col,
    float* __restrict__ gated, float* __restrict__ stats) {
    int n = blockIdx.x;
    int head = threadIdx.x >> 6;
    int lane = threadIdx.x & 63;
    int g = lane >> 4;         // edge group 0..3
    int subl = lane & 15;      // 8 channels per lane
    const int hbase = head * CH;
    const int off = hbase + subl * 8;
    const float* qrow = qb + (size_t)n * HCW + off;
    const float4 q0 = *(const float4*)qrow;
    const float4 q1 = *(const float4*)(qrow + 4);
    int beg = offs[n], end = offs[n + 1];
    const float scale = 0.08838834764831845f;  // 1/sqrt(128)

    float mA = -INFINITY, sA = 0.f, mB = -INFINITY, sB = 0.f;
    float4 a0A = {0.f, 0.f, 0.f, 0.f}, a1A = {0.f, 0.f, 0.f, 0.f};
    float4 a0B = {0.f, 0.f, 0.f, 0.f}, a1B = {0.f, 0.f, 0.f, 0.f};

    for (int p = beg + g; p < end; p += 8) {
        int pB = p + 4;
        bool hasB = (pB < end);
        int snA = col[p];
        int snB = hasB ? col[pB] : snA;
        const unsigned short* bA = kv16 + ((size_t)snA << 10) + off;
        const unsigned short* bB = kv16 + ((size_t)snB << 10) + off;
        uint4 kkA = *(const uint4*)bA;
        uint4 vvA = *(const uint4*)(bA + 512);
        uint4 kkB = *(const uint4*)bB;
        uint4 vvB = *(const uint4*)(bB + 512);
        float dA = dot8(q0, q1, kkA);
        float dB = dot8(q0, q1, kkB);
        dA = red16(dA);
        dB = red16(dB);
        float lA = dA * scale;
        float lB = dB * scale;
        if (lA <= mA + 8.f) {             // fast path: no rescale
            float w = __expf(lA - mA);
            sA += w;
            a0A.x += w * lo16(vvA.x); a0A.y += w * hi16(vvA.x);
            a0A.z += w * lo16(vvA.y); a0A.w += w * hi16(vvA.y);
            a1A.x += w * lo16(vvA.z); a1A.y += w * hi16(vvA.z);
            a1A.z += w * lo16(vvA.w); a1A.w += w * hi16(vvA.w);
        } else {                          // rescale (first edge & rare growth)
            float sc = __expf(mA - lA);   // mA=-inf -> 0
            sA = sA * sc + 1.f;
            a0A.x = a0A.x * sc + lo16(vvA.x); a0A.y = a0A.y * sc + hi16(vvA.x);
            a0A.z = a0A.z * sc + lo16(vvA.y); a0A.w = a0A.w * sc + hi16(vvA.y);
            a1A.x = a1A.x * sc + lo16(vvA.z); a1A.y = a1A.y * sc + hi16(vvA.z);
            a1A.z = a1A.z * sc + lo16(vvA.w); a1A.w = a1A.w * sc + hi16(vvA.w);
            mA = lA;
        }
        if (hasB) {
            if (lB <= mB + 8.f) {
                float w = __expf(lB - mB);
                sB += w;
                a0B.x += w * lo16(vvB.x); a0B.y += w * hi16(vvB.x);
                a0B.z += w * lo16(vvB.y); a0B.w += w * hi16(vvB.y);
                a1B.x += w * lo16(vvB.z); a1B.y += w * hi16(vvB.z);
                a1B.z += w * lo16(vvB.w); a1B.w += w * hi16(vvB.w);
            } else {
                float sc = __expf(mB - lB);
                sB = sB * sc + 1.f;
                a0B.x = a0B.x * sc + lo16(vvB.x); a0B.y = a0B.y * sc + hi16(vvB.x);
                a0B.z = a0B.z * sc + lo16(vvB.y); a0B.w = a0B.w * sc + hi16(vvB.y);
                a1B.x = a1B.x * sc + lo16(vvB.z); a1B.y = a1B.y * sc + hi16(vvB.z);
                a1B.z = a1B.z * sc + lo16(vvB.w); a1B.w = a1B.w * sc + hi16(vvB.w);
                mB = lB;
            }
        }
    }
    // merge B into A (per-lane)
    {
        float mn = fmaxf(mA, mB);
        float c1 = (sA > 0.f) ? __expf(mA - mn) : 0.f;
        float c2 = (sB > 0.f) ? __expf(mB - mn) : 0.f;
        sA = sA * c1 + sB * c2;
        a0A.x = a0A.x * c1 + a0B.x * c2; a0A.y = a0A.y * c1 + a0B.y * c2;
        a0A.z = a0A.z * c1 + a0B.z * c2; a0A.w = a0A.w * c1 + a0B.w * c2;
        a1A.x = a1A.x * c1 + a1B.x * c2; a1A.y = a1A.y * c1 + a1B.y * c2;
        a1A.z = a1A.z * c1 + a1B.z * c2; a1A.w = a1A.w * c1 + a1B.w * c2;
        mA = mn;
    }
    // merge the 4 group states (lane^16, lane^32 hold same channels)
#pragma unroll
    for (int off2 = 16; off2 <= 32; off2 <<= 1) {
        float m_o = __shfl_xor(mA, off2, 64);
        float s_o = __shfl_xor(sA, off2, 64);
        float4 b0, b1;
        b0.x = __shfl_xor(a0A.x, off2, 64); b0.y = __shfl_xor(a0A.y, off2, 64);
        b0.z = __shfl_xor(a0A.z, off2, 64); b0.w = __shfl_xor(a0A.w, off2, 64);
        b1.x = __shfl_xor(a1A.x, off2, 64); b1.y = __shfl_xor(a1A.y, off2, 64);
        b1.z = __shfl_xor(a1A.z, off2, 64); b1.w = __shfl_xor(a1A.w, off2, 64);
        float mn = fmaxf(mA, m_o);
        float c1 = (sA > 0.f) ? __expf(mA - mn) : 0.f;
        float c2 = (s_o > 0.f) ? __expf(m_o - mn) : 0.f;
        sA = sA * c1 + s_o * c2;
        a0A.x = a0A.x * c1 + b0.x * c2; a0A.y = a0A.y * c1 + b0.y * c2;
        a0A.z = a0A.z * c1 + b0.z * c2; a0A.w = a0A.w * c1 + b0.w * c2;
        a1A.x = a1A.x * c1 + b1.x * c2; a1A.y = a1A.y * c1 + b1.y * c2;
        a1A.z = a1A.z * c1 + b1.z * c2; a1A.w = a1A.w * c1 + b1.w * c2;
        mA = mn;
    }
    float inv = (sA > 0.f) ? 1.f / sA : 0.f;

    __shared__ float att_s[512];
    if (g == 0) {
        float4 o0 = {a0A.x * inv, a0A.y * inv, a0A.z * inv, a0A.w * inv};
        float4 o1 = {a1A.x * inv, a1A.y * inv, a1A.z * inv, a1A.w * inv};
        *(float4*)(att_s + off) = o0;
        *(float4*)(att_s + off + 4) = o1;
    }
    __syncthreads();

    // beta gate: channels c0 = head*128 + 2*lane, c1 = c0+1
    int c0 = hbase + lane * 2;
    float o0 = att_s[c0], o1 = att_s[c0 + 1];
    float2 sk = ((const float2*)(skip + (size_t)n * HCW + hbase))[lane];
    float part = o0 * Wb[c0] + o1 * Wb[c0 + 1]
               + sk.x * Wb[512 + c0] + sk.y * Wb[512 + c0 + 1]
               + (o0 - sk.x) * Wb[1024 + c0] + (o1 - sk.y) * Wb[1024 + c0 + 1];
    part = red64(part);
    __shared__ float red[4];
    if (lane == 0) red[head] = part;
    __syncthreads();
    float tot = red[0] + red[1] + red[2] + red[3];
    float beta = 1.f / (1.f + __expf(-tot));
    float gx = beta * sk.x + (1.f - beta) * o0;
    float gy = beta * sk.y + (1.f - beta) * o1;
    ((float2*)(gated + (size_t)n * HCW + hbase))[lane] = make_float2(gx, gy);

    // LN partial sums -> bucketed atomics
    float ls = red64(gx + gy);
    float lq = red64(gx * gx + gy * gy);
    __shared__ float r2[8];
    if (lane == 0) { r2[head] = ls; r2[4 + head] = lq; }
    __syncthreads();
    if (threadIdx.x == 0) {
        int b = n & (NBUCK - 1);
        atomicAdd(&stats[b * 16], r2[0] + r2[1] + r2[2] + r2[3]);
        atomicAdd(&stats[b * 16 + 1], r2[4] + r2[5] + r2[6] + r2[7]);
    }
}

// ---------------- LN + proj MFMA + residual + relu ----------------
// 64-row tiles, 8 waves (512 thr): wave w computes 16 rows x 64 cols.
__global__ __launch_bounds__(512) void k_proj_mfma(
    const float* __restrict__ gated,           // [NN][512]
    const unsigned short* __restrict__ Wpt,    // [128][512] layer slice
    const float* __restrict__ bp,
    const float* __restrict__ lw, const float* __restrict__ lb,
    const float* __restrict__ stats,
    float* __restrict__ h, unsigned short* __restrict__ h_bf) {
    __shared__ unsigned short As[64 * 128];    // 16KB
    __shared__ unsigned short Bs[128 * 128];   // 32KB
    int row0 = blockIdx.x * 64;
    int t = threadIdx.x;
    float ssum = 0.f, sq = 0.f;
#pragma unroll 16
    for (int i = 0; i < NBUCK; i++) { ssum += stats[i * 16]; sq += stats[i * 16 + 1]; }
    const float invM = 1.f / (NN * 512.f);
    float mean = ssum * invM;
    float ms = sq * invM - mean * mean;
    float rstd = 1.f / (sqrtf(fmaxf(ms, 0.f)) + LN_EPS);
    int wave = t >> 6, lane = t & 63;
    int wr = (wave >> 1) * 16, wc = (wave & 1) * 64;
    int lr = lane & 15, lk = lane >> 4;
    f32x4 acc[4] = {};
    for (int kc = 0; kc < 4; kc++) {
        __syncthreads();
#pragma unroll
        for (int i = 0; i < 2; i++) {
            int c = t + i * 512;
            int r = c >> 4, cc = c & 15;
            int gr = row0 + r;
            int gk = kc * 128 + cc * 8;
            unsigned short u[8];
            if (gr < NN) {
                const float* gp = gated + (size_t)gr * 512 + gk;
#pragma unroll
                for (int j = 0; j < 8; j++) {
                    float v = (gp[j] - mean) * rstd * lw[gk + j] + lb[gk + j];
                    u[j] = f2bf(v);
                }
            } else {
#pragma unroll
                for (int j = 0; j < 8; j++) u[j] = 0;
            }
            int sc = (r << 4) | (cc ^ (r & 7));
            *(uint4*)(As + sc * 8) = *(uint4*)u;
        }
#pragma unroll
        for (int i = 0; i < 4; i++) {
            int c = t + i * 512;
            int r = c >> 4, cc = c & 15;
            uint4 v = *(const uint4*)(Wpt + (size_t)r * 512 + kc * 128 + cc * 8);
            int sc = (r << 4) | (cc ^ (r & 7));
            *(uint4*)(Bs + sc * 8) = v;
        }
        __syncthreads();
#pragma unroll
        for (int ks = 0; ks < 4; ks++) {
            bf16x8 a, b[4];
            {
                int r = wr + lr;
                int cc = (ks * 4 + lk) ^ (r & 7);
                a = *(const bf16x8*)(As + (((r << 4) | cc) * 8));
            }
#pragma unroll
            for (int ni = 0; ni < 4; ni++) {
                int r = wc + ni * 16 + lr;
                int cc = (ks * 4 + lk) ^ (r & 7);
                b[ni] = *(const bf16x8*)(Bs + (((r << 4) | cc) * 8));
            }
#pragma unroll
            for (int ni = 0; ni < 4; ni++)
                acc[ni] = __builtin_amdgcn_mfma_f32_16x16x32_bf16(a, b[ni], acc[ni], 0, 0, 0);
        }
    }
#pragma unroll
    for (int ni = 0; ni < 4; ni++) {
        int gc = wc + ni * 16 + lr;  // 0..127
        float bias = bp[gc];
        int gr0 = row0 + wr + 4 * lk;
#pragma unroll
        for (int r = 0; r < 4; r++) {
            int grr = gr0 + r;
            if (grr < NN) {
                float o = acc[ni][r] + bias + h[(size_t)grr * 128 + gc];
                o = fmaxf(o, 0.f);
                h[(size_t)grr * 128 + gc] = o;
                h_bf[(size_t)grr * 128 + gc] = f2bf(o);
            }
        }
    }
}

// ---------------- output projection ----------------
__global__ void k_out(const float* __restrict__ h, const float* __restrict__ W,
                      const float* __restrict__ b, float* __restrict__ out) {
    int i = blockIdx.x * blockDim.x + threadIdx.x;
    if (i >= NN * 5) return;
    int n = i / 5, j = i % 5;
    float acc = b[j];
    for (int k = 0; k < 128; k++) acc += h[(size_t)n * 128 + k] * W[k * 5 + j];
    out[i] = acc;
}

extern "C" void kernel_launch(void* const* d_in, const int* in_sizes, int n_in,
                              void* d_out, int out_size, void* d_ws, size_t ws_size,
                              hipStream_t stream) {
    const float* x     = (const float*)d_in[0];
    const int* ei      = (const int*)d_in[1];
    const float* W_in  = (const float*)d_in[2];
    const float* b_in  = (const float*)d_in[3];
    const float* W_out = (const float*)d_in[4];
    const float* b_out = (const float*)d_in[5];
    const float* Wq    = (const float*)d_in[6];
    const float* bq    = (const float*)d_in[7];
    const float* Wk    = (const float*)d_in[8];
    const float* bk    = (const float*)d_in[9];
    const float* Wv    = (const float*)d_in[10];
    const float* bv    = (const float*)d_in[11];
    const float* Wsk   = (const float*)d_in[12];
    const float* bsk   = (const float*)d_in[13];
    const float* Wbeta = (const float*)d_in[14];
    const float* ln_w  = (const float*)d_in[15];
    const float* ln_b  = (const float*)d_in[16];
    const float* Wproj = (const float*)d_in[17];
    const float* bproj = (const float*)d_in[18];
    float* out = (float*)d_out;

    // workspace layout
    float* h     = (float*)d_ws;                    // N*128
    float* qb    = h + (size_t)NN * 128;            // N*512
    float* sb    = qb + (size_t)NN * 512;           // N*512
    float* stats = sb + (size_t)NN * 512;           // L*NBUCK*16
    int* offs = (int*)(stats + NLAYERS * NBUCK * 16);  // N+1
    int* cnt  = offs + (NN + 1);
    int* fill = cnt + NN;
    int* col  = fill + NN;                          // E
    unsigned short* h_bf = (unsigned short*)(((uintptr_t)(col + NE) + 15) & ~(uintptr_t)15);
    unsigned short* kv16 = h_bf + (size_t)NN * 128;                // N*1024 interleaved K|V
    unsigned short* wt_qkvs = kv16 + (size_t)NN * 1024;            // L*2048*128
    unsigned short* wpt = wt_qkvs + (size_t)NLAYERS * 2048 * 128;  // L*128*512
    float* gated = qb;  // alias (block n reads q row n before writing row n)

    const int* src = ei;
    const int* dst = ei + NE;

    k_init<<<(NN + 255) / 256, 256, 0, stream>>>(cnt, fill, stats);
    k_count<<<(NE + 255) / 256, 256, 0, stream>>>(dst, cnt);
    k_scan<<<1, 1024, 0, stream>>>(cnt, offs);
    k_fill<<<(NE + 255) / 256, 256, 0, stream>>>(src, dst, offs, fill, col);
    {
        int tot = NLAYERS * 2048 * 128 + NLAYERS * 128 * 512;
        k_wconv<<<(tot + 255) / 256, 256, 0, stream>>>(Wq, Wk, Wv, Wsk, Wproj, wt_qkvs, wpt);
    }
    k_inproj<<<NN, 128, 0, stream>>>(x, W_in, b_in, h, h_bf);

    for (int l = 0; l < NLAYERS; ++l) {
        const unsigned short* Wt_ = wt_qkvs + (size_t)l * 2048 * 128;
        const unsigned short* Wp_ = wpt + (size_t)l * 128 * 512;
        const float* bq_ = bq + l * 512;
        const float* bk_ = bk + l * 512;
        const float* bv_ = bv + l * 512;
        const float* bs_ = bsk + l * 512;
        const float* Wb_ = Wbeta + (size_t)l * 1536;
        const float* lw_ = ln_w + l * 512;
        const float* lb_ = ln_b + l * 512;
        const float* bp_ = bproj + l * 128;
        float* st = stats + (size_t)l * NBUCK * 16;

        dim3 g1((NN + 127) / 128, 16);
        k_qkvs_mfma<<<g1, 256, 0, stream>>>(h_bf, Wt_, bq_, bk_, bv_, bs_,
                                            qb, kv16, sb);
        k_attn_beta<<<NN, 256, 0, stream>>>(qb, kv16, sb, Wb_, offs, col, gated, st);
        k_proj_mfma<<<(NN + 63) / 64, 512, 0, stream>>>(gated, Wp_, bp_, lw_, lb_, st, h, h_bf);
    }
    k_out<<<(NN * 5 + 255) / 256, 256, 0, stream>>>(h, W_out, b_out, out);
}